// Round 6
// baseline (23807.314 us; speedup 1.0000x reference)
//
#include <hip/hip_runtime.h>

typedef unsigned short u16;
typedef unsigned int   u32;
typedef _Float16 v8hf __attribute__((ext_vector_type(8)));
typedef float  f32x4 __attribute__((ext_vector_type(4)));

// ---------------- problem constants ----------------
static constexpr int B_   = 2048;
static constexpr int T_   = 64;
static constexpr int D_   = 64;
static constexpr int H_   = 256;
static constexpr int NL_  = 10;
static constexpr int FUT_ = 96;
static constexpr int NBLK = 128;     // B/16

// workspace layout (bytes)
static constexpr size_t WF_LAYER_ELEMS = 524288;          // u16 per layer (1 MiB)
static constexpr size_t SEQ_OFF        = 16u << 20;       // seq buffer at +16 MiB
// seq: fp16 [NBLK][T][16][256]  = 64 MiB

// ---------------- small helpers ----------------
__device__ __forceinline__ u16 f2h(float f) {
  _Float16 h = (_Float16)f;                 // RNE v_cvt_f16_f32
  return __builtin_bit_cast(u16, h);
}
__device__ __forceinline__ float h2f(u16 b) {
  return (float)__builtin_bit_cast(_Float16, b);
}
__device__ __forceinline__ float rcp_(float x) { return __builtin_amdgcn_rcpf(x); }
__device__ __forceinline__ float fsig(float x) { return rcp_(1.f + __expf(-x)); }
__device__ __forceinline__ float ftanh(float x) {
  float e = __expf(-2.f * fabsf(x));
  float t = (1.f - e) * rcp_(1.f + e);
  return copysignf(t, x);
}

// ---------------- weight packing (fp16 B-fragment order) ----------------
// Fragment (gnt, kc): element (lane, i) = Wcat[g = gnt*16 + (lane&15)][k = kc*32 + (lane>>4)*8 + i]
__global__ void pack_weights_v4(const float* __restrict__ Wih0,
                                const float* __restrict__ Wih,
                                const float* __restrict__ Whh,
                                u16* __restrict__ wf) {
  int gid = blockIdx.x * 256 + threadIdx.x;
  int l   = gid >> 16;            // 65536 frag-threads per layer
  if (l >= NL_) return;
  int rem  = gid & 65535;
  int gnt  = rem >> 10;           // 0..63
  int kc   = (rem >> 6) & 15;     // 0..15
  int lane = rem & 63;
  const int NKC = (l == 0) ? 10 : 16;
  if (kc >= NKC) return;
  const int KX = (l == 0) ? 64 : 256;

  int g  = gnt * 16 + (lane & 15);
  int k0 = kc * 32 + (lane >> 4) * 8;

  float v[8];
#pragma unroll
  for (int i = 0; i < 8; ++i) {
    int k = k0 + i;
    float x;
    if (l == 0) x = (k < KX) ? Wih0[g * 64 + k] : Whh[g * 256 + (k - KX)];
    else        x = (k < KX) ? Wih[(size_t)((l - 1) * 1024 + g) * 256 + k]
                             : Whh[(size_t)(l * 1024 + g) * 256 + (k - KX)];
    v[i] = x;
  }
  u32 pk[4];
#pragma unroll
  for (int i = 0; i < 4; ++i)
    pk[i] = (u32)f2h(v[2 * i]) | ((u32)f2h(v[2 * i + 1]) << 16);
  uint4 val; val.x = pk[0]; val.y = pk[1]; val.z = pk[2]; val.w = pk[3];
  u16* dst = wf + (size_t)l * WF_LAYER_ELEMS + ((size_t)(gnt * NKC + kc) * 64 + lane) * 8;
  *(uint4*)dst = val;
}

// ---------------- LSTM layer v4 ----------------
// One block = 16 batch rows, 512 threads = 8 waves = 4 gates x 2 K-halves.
// Wave (w, kh): gate w (cols w*256..), kc in [kh*KCL, (kh+1)*KCL).
// A = [x_t ; h_{t-1}] 16 x K fp16 in LDS (row stride 1024B fixed, XOR swizzle (row&7)<<4).
// W fragments streamed from L2 with a double-buffered register prefetch
// (static indices only). Partial gate sums reduced through glds[2] in phase 3.
template <int NKC, int KCL, int KX, bool L0>
__global__ __launch_bounds__(512, 2) void lstm_layer_v4(
    const float* __restrict__ X,      // only for L0
    u16* __restrict__ seq,            // [NBLK][T][16][256] fp16, in-place x->h
    const u16* __restrict__ wf,       // this layer's packed weights
    const float* __restrict__ bias)   // [1024]
{
  __shared__ __align__(16) u16  Ahi[16 * 512];        // 16 KiB (rows at 1024 B stride)
  __shared__ float glds[2][4][16][260];               // 2 x 65 KiB partial-sum buffers

  const int tid  = threadIdx.x;
  const int wid  = tid >> 6;           // 0..7
  const int w    = wid & 3;            // gate
  const int kh   = wid >> 2;           // K-half
  const int lane = tid & 63;
  const int bid  = blockIdx.x;
  const int arow = lane & 15;          // A row / D col within MFMA
  const int ahi  = lane >> 4;          // k-group / D row-group
  const int aswz = (arow & 7) << 4;
  const int kc0  = kh * KCL;

  // zero h-part of A rows (512 B per row starting at byte KX*2)
  {
    int r = tid >> 5, o = (tid & 31) * 16;
    uint4 z; z.x = z.y = z.z = z.w = 0;
    *(uint4*)((char*)Ahi + r * 1024 + KX * 2 + o) = z;
  }

  // phase-3 state: thread owns col j = tid&255, rows rh*8..rh*8+7
  const int j  = tid & 255;
  const int rh = tid >> 8;
  float c[8];
#pragma unroll
  for (int q = 0; q < 8; ++q) c[q] = 0.f;

  float bv[16];
  if (kh == 0) {
#pragma unroll
    for (int nt = 0; nt < 16; ++nt) bv[nt] = bias[w * 256 + nt * 16 + arow];
  }

  // W base for this wave: fragment (gnt = w*16+nt, kc = kc0+i) at
  // wf[((gnt*NKC + kc)*64 + lane)*8]
  const u16* wb = wf + ((size_t)(w * 16) * NKC + kc0) * 512 + (size_t)lane * 8;

  for (int t = 0; t < T_; ++t) {
    // ---- phase 1: load x_t into A (swizzled) ----
    if constexpr (L0) {
      if (tid < 256) {
        int r = tid >> 4, seg = tid & 15;
        const float4 xv = *(const float4*)(X + ((size_t)(bid * 16 + r) * T_ + t) * D_ + seg * 4);
        uint2 pk;
        pk.x = (u32)f2h(xv.x) | ((u32)f2h(xv.y) << 16);
        pk.y = (u32)f2h(xv.z) | ((u32)f2h(xv.w) << 16);
        *(uint2*)((char*)Ahi + r * 1024 + ((seg * 8) ^ ((r & 7) << 4))) = pk;
      }
    } else {
      int r = tid >> 5, seg = tid & 31;
      uint4 v = *(const uint4*)(seq + ((((size_t)bid * T_ + t) * 16 + r) << 8) + seg * 8);
      *(uint4*)((char*)Ahi + r * 1024 + ((seg * 16) ^ ((r & 7) << 4))) = v;
    }
    __syncthreads();

    // ---- phase 2: partial gates = A[:, kc0..kc0+KCL) @ W^T (+bias for kh=0) ----
    v8hf a[KCL];
#pragma unroll
    for (int i = 0; i < KCL; ++i)
      a[i] = *(const v8hf*)((const char*)Ahi + arow * 1024 + (((kc0 + i) * 64 + ahi * 16) ^ aswz));

    // double-buffered W prefetch; all indices compile-time (full unroll)
    v8hf bf0[KCL], bf1[KCL];
#pragma unroll
    for (int i = 0; i < KCL; ++i)
      bf0[i] = *(const v8hf*)(const void*)(wb + (size_t)(0 * NKC + i) * 512);

#pragma unroll
    for (int nt = 0; nt < 16; ++nt) {
      // issue next tile's loads first
      if (nt < 15) {
        if ((nt & 1) == 0) {
#pragma unroll
          for (int i = 0; i < KCL; ++i)
            bf1[i] = *(const v8hf*)(const void*)(wb + (size_t)((nt + 1) * NKC + i) * 512);
        } else {
#pragma unroll
          for (int i = 0; i < KCL; ++i)
            bf0[i] = *(const v8hf*)(const void*)(wb + (size_t)((nt + 1) * NKC + i) * 512);
        }
      }
      f32x4 acc;
      if (kh == 0) { acc[0] = bv[nt]; acc[1] = bv[nt]; acc[2] = bv[nt]; acc[3] = bv[nt]; }
      else         { acc[0] = 0.f;    acc[1] = 0.f;    acc[2] = 0.f;    acc[3] = 0.f;    }
      if ((nt & 1) == 0) {
#pragma unroll
        for (int i = 0; i < KCL; ++i)
          acc = __builtin_amdgcn_mfma_f32_16x16x32_f16(a[i], bf0[i], acc, 0, 0, 0);
      } else {
#pragma unroll
        for (int i = 0; i < KCL; ++i)
          acc = __builtin_amdgcn_mfma_f32_16x16x32_f16(a[i], bf1[i], acc, 0, 0, 0);
      }
#pragma unroll
      for (int q = 0; q < 4; ++q)
        glds[kh][w][ahi * 4 + q][nt * 16 + arow] = acc[q];  // D: row=(lane>>4)*4+q, col=lane&15
    }
    __syncthreads();

    // ---- phase 3: reduce K-halves + nonlinearity + state update ----
    u16* srow = seq + ((((size_t)bid * T_ + t) * 16) << 8) + j;
#pragma unroll
    for (int q = 0; q < 8; ++q) {
      int r = rh * 8 + q;
      float iv = glds[0][0][r][j] + glds[1][0][r][j];
      float fv = glds[0][1][r][j] + glds[1][1][r][j];
      float gv = glds[0][2][r][j] + glds[1][2][r][j];
      float ov = glds[0][3][r][j] + glds[1][3][r][j];
      float cn = fsig(fv) * c[q] + fsig(iv) * ftanh(gv);
      c[q] = cn;
      float h = fsig(ov) * ftanh(cn);
      u16 hb = f2h(h);
      srow[(size_t)r << 8] = hb;                             // global (next layer / tail)
      *(u16*)((char*)Ahi + r * 1024 + (((KX + j) * 2) ^ ((r & 7) << 4))) = hb;  // A h-part
    }
    // next phase-1 writes the x-part (disjoint from h-part); the barrier after
    // phase 1 orders phase-3 LDS/global effects before phase 2 of t+1.
  }
}

// ---------------- tail (encoder / sample / decoder) ----------------
template <int N, int K, bool RELU>
__device__ __forceinline__ void dense(const float (*__restrict__ in)[512],
                                      float (*__restrict__ out)[512],
                                      const float* __restrict__ W,
                                      const float* __restrict__ bg, int tid) {
  for (int e = tid; e < 16 * N; e += 256) {
    int r = e / N, n = e - r * N;
    const float* wr = W + (size_t)n * K;
    const float* ar = in[r];
    float4 acc = {0.f, 0.f, 0.f, 0.f};
    for (int k = 0; k < K; k += 4) {
      float4 wv = *(const float4*)(wr + k);
      float4 av = *(const float4*)(ar + k);
      acc.x = fmaf(wv.x, av.x, acc.x);
      acc.y = fmaf(wv.y, av.y, acc.y);
      acc.z = fmaf(wv.z, av.z, acc.z);
      acc.w = fmaf(wv.w, av.w, acc.w);
    }
    float s = bg[n] + acc.x + acc.y + acc.z + acc.w;
    out[r][n] = RELU ? fmaxf(s, 0.f) : s;
  }
}

template <int K>
__device__ __forceinline__ float dotK(const float* __restrict__ a, const float* __restrict__ w) {
  float4 acc = {0.f, 0.f, 0.f, 0.f};
#pragma unroll
  for (int k = 0; k < K; k += 4) {
    float4 wv = *(const float4*)(w + k);
    float4 av = *(const float4*)(a + k);
    acc.x = fmaf(wv.x, av.x, acc.x);
    acc.y = fmaf(wv.y, av.y, acc.y);
    acc.z = fmaf(wv.z, av.z, acc.z);
    acc.w = fmaf(wv.w, av.w, acc.w);
  }
  return acc.x + acc.y + acc.z + acc.w;
}

struct TailArgs {
  const u16* seq;
  const float *ef1w, *ef1b, *ef2w, *ef2b;
  const float *mean_w, *mean_b, *logvar_w, *logvar_b;
  const float *scale_w, *scale_b, *shape_w, *shape_b;
  const float *df1w, *df1b, *df2w, *df2b, *outw, *outb, *finw, *finb;
  const float *pi, *eps, *u, *choice;
  float* out;
};

__global__ __launch_bounds__(256) void tail_kernel_v4(TailArgs A) {
  __shared__ float a0[16][512];
  __shared__ float a1[16][512];
  const int tid = threadIdx.x, bid = blockIdx.x;

  // last hidden state (t = T-1) of final layer
  for (int e = tid; e < 16 * 256; e += 256) {
    int r = e >> 8, jj = e & 255;
    a0[r][jj] = h2f(A.seq[((((size_t)bid * T_ + (T_ - 1)) * 16 + r) << 8) + jj]);
  }
  __syncthreads();

  dense<128, 256, true>(a0, a1, A.ef1w, A.ef1b, tid); __syncthreads();
  dense<64, 128, true>(a1, a0, A.ef2w, A.ef2b, tid);  __syncthreads();

  // heads + reparameterization / GPD mixture
  const float pi = *A.pi;
  for (int e = tid; e < 16 * 64; e += 256) {
    int r = e >> 6, n = e & 63;
    size_t rg = (size_t)bid * 16 + r;
    float m  = dotK<64>(a0[r], A.mean_w   + n * 64) + A.mean_b[n];
    float lv = dotK<64>(a0[r], A.logvar_w + n * 64) + A.logvar_b[n];
    float sc = __expf(dotK<64>(a0[r], A.scale_w + n * 64) + A.scale_b[n]);
    float sh = dotK<64>(a0[r], A.shape_w + n * 64) + A.shape_b[n];
    A.out[196608 + rg * 64 + n] = m;    // z_mean
    A.out[327680 + rg * 64 + n] = lv;   // z_logvar
    A.out[458752 + rg * 64 + n] = sc;   // z_scale
    A.out[589824 + rg * 64 + n] = sh;   // z_shape
    float zg = m + A.eps[rg * 64 + n] * __expf(0.5f * lv);
    float L  = log1pf(-A.u[rg * 64 + n]);
    float zp = sc / sh * (__expf(-sh * L) - 1.f);
    a1[r][n] = (A.choice[rg] < pi) ? zg : zp;
  }
  __syncthreads();

  dense<128, 64, true>(a1, a0, A.df1w, A.df1b, tid);   __syncthreads();
  dense<500, 128, true>(a0, a1, A.df2w, A.df2b, tid);  __syncthreads();
  dense<96, 500, false>(a1, a0, A.outw, A.outb, tid);  __syncthreads();
  dense<96, 96, false>(a0, a1, A.finw, A.finb, tid);   __syncthreads();

  for (int e = tid; e < 16 * FUT_; e += 256) {
    int r = e / FUT_, n = e - r * FUT_;
    A.out[((size_t)bid * 16 + r) * FUT_ + n] = a1[r][n];
  }
}

// ---------------- launch ----------------
extern "C" void kernel_launch(void* const* d_in, const int* in_sizes, int n_in,
                              void* d_out, int out_size, void* d_ws, size_t ws_size,
                              hipStream_t stream) {
  (void)in_sizes; (void)n_in; (void)out_size; (void)ws_size;

  const float* X      = (const float*)d_in[0];
  const float* Wih0   = (const float*)d_in[1];
  const float* Wih    = (const float*)d_in[2];
  const float* Whh    = (const float*)d_in[3];
  const float* b      = (const float*)d_in[4];
  const float* ef1w   = (const float*)d_in[5];
  const float* ef1b   = (const float*)d_in[6];
  const float* ef2w   = (const float*)d_in[7];
  const float* ef2b   = (const float*)d_in[8];
  const float* mean_w = (const float*)d_in[9];
  const float* mean_b = (const float*)d_in[10];
  const float* logvar_w = (const float*)d_in[11];
  const float* logvar_b = (const float*)d_in[12];
  const float* scale_w  = (const float*)d_in[13];
  const float* scale_b  = (const float*)d_in[14];
  const float* shape_w  = (const float*)d_in[15];
  const float* shape_b  = (const float*)d_in[16];
  const float* df1w   = (const float*)d_in[17];
  const float* df1b   = (const float*)d_in[18];
  const float* df2w   = (const float*)d_in[19];
  const float* df2b   = (const float*)d_in[20];
  const float* outw   = (const float*)d_in[21];
  const float* outb   = (const float*)d_in[22];
  const float* finw   = (const float*)d_in[23];
  const float* finb   = (const float*)d_in[24];
  const float* pi_g   = (const float*)d_in[25];
  const float* eps    = (const float*)d_in[26];
  const float* u      = (const float*)d_in[27];
  const float* choice = (const float*)d_in[28];

  u16* wf  = (u16*)d_ws;
  u16* seq = (u16*)((char*)d_ws + SEQ_OFF);
  float* out = (float*)d_out;

  pack_weights_v4<<<2560, 256, 0, stream>>>(Wih0, Wih, Whh, wf);

  // LSTM stack (in-place on seq; layer 0 reads X)
  lstm_layer_v4<10, 5, 64, true><<<NBLK, 512, 0, stream>>>(X, seq, wf, b);
  for (int l = 1; l < NL_; ++l)
    lstm_layer_v4<16, 8, 256, false><<<NBLK, 512, 0, stream>>>(nullptr, seq,
        wf + (size_t)l * WF_LAYER_ELEMS, b + l * 1024);

  TailArgs A;
  A.seq = seq;
  A.ef1w = ef1w; A.ef1b = ef1b; A.ef2w = ef2w; A.ef2b = ef2b;
  A.mean_w = mean_w; A.mean_b = mean_b; A.logvar_w = logvar_w; A.logvar_b = logvar_b;
  A.scale_w = scale_w; A.scale_b = scale_b; A.shape_w = shape_w; A.shape_b = shape_b;
  A.df1w = df1w; A.df1b = df1b; A.df2w = df2w; A.df2b = df2b;
  A.outw = outw; A.outb = outb; A.finw = finw; A.finb = finb;
  A.pi = pi_g; A.eps = eps; A.u = u; A.choice = choice;
  A.out = out;
  tail_kernel_v4<<<NBLK, 512 / 2, 0, stream>>>(A);
}

// Round 8
// 23446.893 us; speedup vs baseline: 1.0154x; 1.0154x over previous
//
#include <hip/hip_runtime.h>

typedef unsigned short u16;
typedef unsigned int   u32;
typedef _Float16 v8hf __attribute__((ext_vector_type(8)));
typedef float  f32x4 __attribute__((ext_vector_type(4)));

// ---------------- problem constants ----------------
static constexpr int B_   = 2048;
static constexpr int T_   = 64;
static constexpr int D_   = 64;
static constexpr int H_   = 256;
static constexpr int NL_  = 10;
static constexpr int FUT_ = 96;
static constexpr int NBLK = 128;     // B/16

// workspace layout (bytes)
static constexpr size_t WF_LAYER_ELEMS = 524288;          // u16 per layer (1 MiB)
static constexpr size_t SEQ_OFF        = 16u << 20;       // seq buffer at +16 MiB
// seq: fp16 [NBLK][T][16][256]  = 64 MiB

// ---------------- small helpers ----------------
__device__ __forceinline__ u16 f2h(float f) {
  _Float16 h = (_Float16)f;                 // RNE v_cvt_f16_f32
  return __builtin_bit_cast(u16, h);
}
__device__ __forceinline__ float h2f(u16 b) {
  return (float)__builtin_bit_cast(_Float16, b);
}
__device__ __forceinline__ float rcp_(float x) { return __builtin_amdgcn_rcpf(x); }
__device__ __forceinline__ float fsig(float x) { return rcp_(1.f + __expf(-x)); }
__device__ __forceinline__ float ftanh(float x) {
  float e = __expf(-2.f * fabsf(x));
  float t = (1.f - e) * rcp_(1.f + e);
  return copysignf(t, x);
}

// ---------------- weight packing (fp16 B-fragment order) ----------------
// Fragment (gnt, kc): element (lane, i) = Wcat[g = gnt*16 + (lane&15)][k = kc*32 + (lane>>4)*8 + i]
__global__ void pack_weights_v6(const float* __restrict__ Wih0,
                                const float* __restrict__ Wih,
                                const float* __restrict__ Whh,
                                u16* __restrict__ wf) {
  int gid = blockIdx.x * 256 + threadIdx.x;
  int l   = gid >> 16;            // 65536 frag-threads per layer
  if (l >= NL_) return;
  int rem  = gid & 65535;
  int gnt  = rem >> 10;           // 0..63
  int kc   = (rem >> 6) & 15;     // 0..15
  int lane = rem & 63;
  const int NKC = (l == 0) ? 10 : 16;
  if (kc >= NKC) return;
  const int KX = (l == 0) ? 64 : 256;

  int g  = gnt * 16 + (lane & 15);
  int k0 = kc * 32 + (lane >> 4) * 8;

  float v[8];
#pragma unroll
  for (int i = 0; i < 8; ++i) {
    int k = k0 + i;
    float x;
    if (l == 0) x = (k < KX) ? Wih0[g * 64 + k] : Whh[g * 256 + (k - KX)];
    else        x = (k < KX) ? Wih[(size_t)((l - 1) * 1024 + g) * 256 + k]
                             : Whh[(size_t)(l * 1024 + g) * 256 + (k - KX)];
    v[i] = x;
  }
  u32 pk[4];
#pragma unroll
  for (int i = 0; i < 4; ++i)
    pk[i] = (u32)f2h(v[2 * i]) | ((u32)f2h(v[2 * i + 1]) << 16);
  uint4 val; val.x = pk[0]; val.y = pk[1]; val.z = pk[2]; val.w = pk[3];
  u16* dst = wf + (size_t)l * WF_LAYER_ELEMS + ((size_t)(gnt * NKC + kc) * 64 + lane) * 8;
  *(uint4*)dst = val;
}

// ---------------- LSTM layer v6 ----------------
// One block = 16 batch rows, 512 threads = 8 waves = 4 gates x 2 K-halves.
// Wave (w, kh): gate w (cols w*256..), kc in [kh*KCL, (kh+1)*KCL).
// A = [x_t ; h_{t-1}] 16 x K fp16 in LDS (row stride 1024B, XOR swizzle (row&7)<<4).
// W fragments streamed from L2/HBM with a DEPTH-4 register prefetch ring
// (3 nt-groups = 24 KiB in flight per wave); prologue issued before the
// phase-1 barrier so its latency hides under A staging.
template <int NKC, int KCL, int KX, bool L0>
__global__ __launch_bounds__(512, 2) void lstm_layer_v6(
    const float* __restrict__ X,      // only for L0
    u16* __restrict__ seq,            // [NBLK][T][16][256] fp16, in-place x->h
    const u16* __restrict__ wf,       // this layer's packed weights
    const float* __restrict__ bias)   // [1024]
{
  __shared__ __align__(16) u16  Ahi[16 * 512];        // 16 KiB (rows at 1024 B stride)
  __shared__ float glds[2][4][16][260];               // 2 x 65 KiB partial-sum buffers

  const int tid  = threadIdx.x;
  const int wid  = tid >> 6;           // 0..7
  const int w    = wid & 3;            // gate
  const int kh   = wid >> 2;           // K-half
  const int lane = tid & 63;
  const int bid  = blockIdx.x;
  const int arow = lane & 15;          // A row / D col within MFMA
  const int ahi  = lane >> 4;          // k-group / D row-group
  const int aswz = (arow & 7) << 4;
  const int kc0  = kh * KCL;

  // zero h-part of A rows (512 B per row starting at byte KX*2)
  {
    int r = tid >> 5, o = (tid & 31) * 16;
    uint4 z; z.x = z.y = z.z = z.w = 0;
    *(uint4*)((char*)Ahi + r * 1024 + KX * 2 + o) = z;
  }

  // phase-3 state: thread owns col j = tid&255, rows rh*8..rh*8+7
  const int j  = tid & 255;
  const int rh = tid >> 8;
  float c[8];
#pragma unroll
  for (int q = 0; q < 8; ++q) c[q] = 0.f;

  float bv[16];
  if (kh == 0) {
#pragma unroll
    for (int nt = 0; nt < 16; ++nt) bv[nt] = bias[w * 256 + nt * 16 + arow];
  }

  // W base for this wave: fragment (gnt = w*16+nt, kc = kc0+i) at
  // wf[((gnt*NKC + kc)*64 + lane)*8]
  const u16* wb = wf + ((size_t)(w * 16) * NKC + kc0) * 512 + (size_t)lane * 8;

  for (int t = 0; t < T_; ++t) {
    // ---- W prefetch prologue: groups nt=0..2 (issued before barrier so the
    //      latency hides under A staging + sync) ----
    v8hf bf[4][KCL];
#pragma unroll
    for (int p = 0; p < 3; ++p)
#pragma unroll
      for (int i = 0; i < KCL; ++i)
        bf[p][i] = *(const v8hf*)(const void*)(wb + (size_t)(p * NKC + i) * 512);

    // ---- phase 1: load x_t into A (swizzled) ----
    if constexpr (L0) {
      if (tid < 256) {
        int r = tid >> 4, seg = tid & 15;
        const float4 xv = *(const float4*)(X + ((size_t)(bid * 16 + r) * T_ + t) * D_ + seg * 4);
        uint2 pk;
        pk.x = (u32)f2h(xv.x) | ((u32)f2h(xv.y) << 16);
        pk.y = (u32)f2h(xv.z) | ((u32)f2h(xv.w) << 16);
        *(uint2*)((char*)Ahi + r * 1024 + ((seg * 8) ^ ((r & 7) << 4))) = pk;
      }
    } else {
      int r = tid >> 5, seg = tid & 31;
      uint4 v = *(const uint4*)(seq + ((((size_t)bid * T_ + t) * 16 + r) << 8) + seg * 8);
      *(uint4*)((char*)Ahi + r * 1024 + ((seg * 16) ^ ((r & 7) << 4))) = v;
    }
    __syncthreads();

    // ---- phase 2: partial gates = A[:, kc0..kc0+KCL) @ W^T (+bias for kh=0) ----
    v8hf a[KCL];
#pragma unroll
    for (int i = 0; i < KCL; ++i)
      a[i] = *(const v8hf*)((const char*)Ahi + arow * 1024 + (((kc0 + i) * 64 + ahi * 16) ^ aswz));

#pragma unroll
    for (int nt = 0; nt < 16; ++nt) {
      // issue group nt+3 into ring slot (nt+3)&3 ; all indices compile-time
      if (nt < 13) {
#pragma unroll
        for (int p = 0; p < 4; ++p) {
          if (p == ((nt + 3) & 3)) {
#pragma unroll
            for (int i = 0; i < KCL; ++i)
              bf[p][i] = *(const v8hf*)(const void*)(wb + (size_t)((nt + 3) * NKC + i) * 512);
          }
        }
      }
      f32x4 acc;
      if (kh == 0) { acc[0] = bv[nt]; acc[1] = bv[nt]; acc[2] = bv[nt]; acc[3] = bv[nt]; }
      else         { acc[0] = 0.f;    acc[1] = 0.f;    acc[2] = 0.f;    acc[3] = 0.f;    }
#pragma unroll
      for (int p = 0; p < 4; ++p) {
        if (p == (nt & 3)) {
#pragma unroll
          for (int i = 0; i < KCL; ++i)
            acc = __builtin_amdgcn_mfma_f32_16x16x32_f16(a[i], bf[p][i], acc, 0, 0, 0);
        }
      }
#pragma unroll
      for (int q = 0; q < 4; ++q)
        glds[kh][w][ahi * 4 + q][nt * 16 + arow] = acc[q];  // D: row=(lane>>4)*4+q, col=lane&15
    }
    __syncthreads();

    // ---- phase 3: reduce K-halves + nonlinearity + state update ----
    u16* srow = seq + ((((size_t)bid * T_ + t) * 16) << 8) + j;
#pragma unroll
    for (int q = 0; q < 8; ++q) {
      int r = rh * 8 + q;
      float iv = glds[0][0][r][j] + glds[1][0][r][j];
      float fv = glds[0][1][r][j] + glds[1][1][r][j];
      float gv = glds[0][2][r][j] + glds[1][2][r][j];
      float ov = glds[0][3][r][j] + glds[1][3][r][j];
      float cn = fsig(fv) * c[q] + fsig(iv) * ftanh(gv);
      c[q] = cn;
      float h = fsig(ov) * ftanh(cn);
      u16 hb = f2h(h);
      srow[(size_t)r << 8] = hb;                             // global (next layer / tail)
      *(u16*)((char*)Ahi + r * 1024 + (((KX + j) * 2) ^ ((r & 7) << 4))) = hb;  // A h-part
    }
    // next phase-1 writes the x-part (disjoint from h-part); the barrier after
    // phase 1 orders phase-3 LDS/global effects before phase 2 of t+1.
  }
}

// ---------------- tail (encoder / sample / decoder) ----------------
template <int N, int K, bool RELU>
__device__ __forceinline__ void dense(const float (*__restrict__ in)[512],
                                      float (*__restrict__ out)[512],
                                      const float* __restrict__ W,
                                      const float* __restrict__ bg, int tid) {
  for (int e = tid; e < 16 * N; e += 256) {
    int r = e / N, n = e - r * N;
    const float* wr = W + (size_t)n * K;
    const float* ar = in[r];
    float4 acc = {0.f, 0.f, 0.f, 0.f};
    for (int k = 0; k < K; k += 4) {
      float4 wv = *(const float4*)(wr + k);
      float4 av = *(const float4*)(ar + k);
      acc.x = fmaf(wv.x, av.x, acc.x);
      acc.y = fmaf(wv.y, av.y, acc.y);
      acc.z = fmaf(wv.z, av.z, acc.z);
      acc.w = fmaf(wv.w, av.w, acc.w);
    }
    float s = bg[n] + acc.x + acc.y + acc.z + acc.w;
    out[r][n] = RELU ? fmaxf(s, 0.f) : s;
  }
}

template <int K>
__device__ __forceinline__ float dotK(const float* __restrict__ a, const float* __restrict__ w) {
  float4 acc = {0.f, 0.f, 0.f, 0.f};
#pragma unroll
  for (int k = 0; k < K; k += 4) {
    float4 wv = *(const float4*)(w + k);
    float4 av = *(const float4*)(a + k);
    acc.x = fmaf(wv.x, av.x, acc.x);
    acc.y = fmaf(wv.y, av.y, acc.y);
    acc.z = fmaf(wv.z, av.z, acc.z);
    acc.w = fmaf(wv.w, av.w, acc.w);
  }
  return acc.x + acc.y + acc.z + acc.w;
}

struct TailArgs {
  const u16* seq;
  const float *ef1w, *ef1b, *ef2w, *ef2b;
  const float *mean_w, *mean_b, *logvar_w, *logvar_b;
  const float *scale_w, *scale_b, *shape_w, *shape_b;
  const float *df1w, *df1b, *df2w, *df2b, *outw, *outb, *finw, *finb;
  const float *pi, *eps, *u, *choice;
  float* out;
};

__global__ __launch_bounds__(256) void tail_kernel_v6(TailArgs A) {
  __shared__ float a0[16][512];
  __shared__ float a1[16][512];
  const int tid = threadIdx.x, bid = blockIdx.x;

  // last hidden state (t = T-1) of final layer
  for (int e = tid; e < 16 * 256; e += 256) {
    int r = e >> 8, jj = e & 255;
    a0[r][jj] = h2f(A.seq[((((size_t)bid * T_ + (T_ - 1)) * 16 + r) << 8) + jj]);
  }
  __syncthreads();

  dense<128, 256, true>(a0, a1, A.ef1w, A.ef1b, tid); __syncthreads();
  dense<64, 128, true>(a1, a0, A.ef2w, A.ef2b, tid);  __syncthreads();

  // heads + reparameterization / GPD mixture
  const float pi = *A.pi;
  for (int e = tid; e < 16 * 64; e += 256) {
    int r = e >> 6, n = e & 63;
    size_t rg = (size_t)bid * 16 + r;
    float m  = dotK<64>(a0[r], A.mean_w   + n * 64) + A.mean_b[n];
    float lv = dotK<64>(a0[r], A.logvar_w + n * 64) + A.logvar_b[n];
    float sc = __expf(dotK<64>(a0[r], A.scale_w + n * 64) + A.scale_b[n]);
    float sh = dotK<64>(a0[r], A.shape_w + n * 64) + A.shape_b[n];
    A.out[196608 + rg * 64 + n] = m;    // z_mean
    A.out[327680 + rg * 64 + n] = lv;   // z_logvar
    A.out[458752 + rg * 64 + n] = sc;   // z_scale
    A.out[589824 + rg * 64 + n] = sh;   // z_shape
    float zg = m + A.eps[rg * 64 + n] * __expf(0.5f * lv);
    float L  = log1pf(-A.u[rg * 64 + n]);
    float zp = sc / sh * (__expf(-sh * L) - 1.f);
    a1[r][n] = (A.choice[rg] < pi) ? zg : zp;
  }
  __syncthreads();

  dense<128, 64, true>(a1, a0, A.df1w, A.df1b, tid);   __syncthreads();
  dense<500, 128, true>(a0, a1, A.df2w, A.df2b, tid);  __syncthreads();
  dense<96, 500, false>(a1, a0, A.outw, A.outb, tid);  __syncthreads();
  dense<96, 96, false>(a0, a1, A.finw, A.finb, tid);   __syncthreads();

  for (int e = tid; e < 16 * FUT_; e += 256) {
    int r = e / FUT_, n = e - r * FUT_;
    A.out[((size_t)bid * 16 + r) * FUT_ + n] = a1[r][n];
  }
}

// ---------------- launch ----------------
extern "C" void kernel_launch(void* const* d_in, const int* in_sizes, int n_in,
                              void* d_out, int out_size, void* d_ws, size_t ws_size,
                              hipStream_t stream) {
  (void)in_sizes; (void)n_in; (void)out_size; (void)ws_size;

  const float* X      = (const float*)d_in[0];
  const float* Wih0   = (const float*)d_in[1];
  const float* Wih    = (const float*)d_in[2];
  const float* Whh    = (const float*)d_in[3];
  const float* b      = (const float*)d_in[4];
  const float* ef1w   = (const float*)d_in[5];
  const float* ef1b   = (const float*)d_in[6];
  const float* ef2w   = (const float*)d_in[7];
  const float* ef2b   = (const float*)d_in[8];
  const float* mean_w = (const float*)d_in[9];
  const float* mean_b = (const float*)d_in[10];
  const float* logvar_w = (const float*)d_in[11];
  const float* logvar_b = (const float*)d_in[12];
  const float* scale_w  = (const float*)d_in[13];
  const float* scale_b  = (const float*)d_in[14];
  const float* shape_w  = (const float*)d_in[15];
  const float* shape_b  = (const float*)d_in[16];
  const float* df1w   = (const float*)d_in[17];
  const float* df1b   = (const float*)d_in[18];
  const float* df2w   = (const float*)d_in[19];
  const float* df2b   = (const float*)d_in[20];
  const float* outw   = (const float*)d_in[21];
  const float* outb   = (const float*)d_in[22];
  const float* finw   = (const float*)d_in[23];
  const float* finb   = (const float*)d_in[24];
  const float* pi_g   = (const float*)d_in[25];
  const float* eps    = (const float*)d_in[26];
  const float* u      = (const float*)d_in[27];
  const float* choice = (const float*)d_in[28];

  u16* wf  = (u16*)d_ws;
  u16* seq = (u16*)((char*)d_ws + SEQ_OFF);
  float* out = (float*)d_out;

  pack_weights_v6<<<2560, 256, 0, stream>>>(Wih0, Wih, Whh, wf);

  // LSTM stack (in-place on seq; layer 0 reads X)
  lstm_layer_v6<10, 5, 64, true><<<NBLK, 512, 0, stream>>>(X, seq, wf, b);
  for (int l = 1; l < NL_; ++l)
    lstm_layer_v6<16, 8, 256, false><<<NBLK, 512, 0, stream>>>(nullptr, seq,
        wf + (size_t)l * WF_LAYER_ELEMS, b + l * 1024);

  TailArgs A;
  A.seq = seq;
  A.ef1w = ef1w; A.ef1b = ef1b; A.ef2w = ef2w; A.ef2b = ef2b;
  A.mean_w = mean_w; A.mean_b = mean_b; A.logvar_w = logvar_w; A.logvar_b = logvar_b;
  A.scale_w = scale_w; A.scale_b = scale_b; A.shape_w = shape_w; A.shape_b = shape_b;
  A.df1w = df1w; A.df1b = df1b; A.df2w = df2w; A.df2b = df2b;
  A.outw = outw; A.outb = outb; A.finw = finw; A.finb = finb;
  A.pi = pi_g; A.eps = eps; A.u = u; A.choice = choice;
  A.out = out;
  tail_kernel_v6<<<NBLK, 256, 0, stream>>>(A);
}

// Round 9
// 18481.349 us; speedup vs baseline: 1.2882x; 1.2687x over previous
//
#include <hip/hip_runtime.h>

typedef unsigned short u16;
typedef unsigned int   u32;
typedef _Float16 v8hf __attribute__((ext_vector_type(8)));
typedef float  f32x4 __attribute__((ext_vector_type(4)));

// ---------------- problem constants ----------------
static constexpr int B_   = 2048;
static constexpr int T_   = 64;
static constexpr int D_   = 64;
static constexpr int H_   = 256;
static constexpr int NL_  = 10;
static constexpr int FUT_ = 96;
static constexpr int NBLK = 128;     // B/16

// workspace layout (bytes)
static constexpr size_t WF_LAYER_ELEMS = 524288;          // u16 per layer (1 MiB)
static constexpr size_t SEQ_OFF        = 16u << 20;       // seq buffer at +16 MiB
// seq: fp16 [NBLK][T][16][256]  = 64 MiB

// ---------------- small helpers ----------------
__device__ __forceinline__ u16 f2h(float f) {
  _Float16 h = (_Float16)f;                 // RNE v_cvt_f16_f32
  return __builtin_bit_cast(u16, h);
}
__device__ __forceinline__ float h2f(u16 b) {
  return (float)__builtin_bit_cast(_Float16, b);
}
__device__ __forceinline__ float rcp_(float x) { return __builtin_amdgcn_rcpf(x); }
__device__ __forceinline__ float fsig(float x) { return rcp_(1.f + __expf(-x)); }
__device__ __forceinline__ float ftanh(float x) {
  float e = __expf(-2.f * fabsf(x));
  float t = (1.f - e) * rcp_(1.f + e);
  return copysignf(t, x);
}

// ---------------- weight packing (fp16 B-fragment order) ----------------
// Fragment (gnt, kc): element (lane, i) = Wcat[g = gnt*16 + (lane&15)][k = kc*32 + (lane>>4)*8 + i]
__global__ void pack_weights_v7(const float* __restrict__ Wih0,
                                const float* __restrict__ Wih,
                                const float* __restrict__ Whh,
                                u16* __restrict__ wf) {
  int gid = blockIdx.x * 256 + threadIdx.x;
  int l   = gid >> 16;            // 65536 frag-threads per layer
  if (l >= NL_) return;
  int rem  = gid & 65535;
  int gnt  = rem >> 10;           // 0..63
  int kc   = (rem >> 6) & 15;     // 0..15
  int lane = rem & 63;
  const int NKC = (l == 0) ? 10 : 16;
  if (kc >= NKC) return;
  const int KX = (l == 0) ? 64 : 256;

  int g  = gnt * 16 + (lane & 15);
  int k0 = kc * 32 + (lane >> 4) * 8;

  float v[8];
#pragma unroll
  for (int i = 0; i < 8; ++i) {
    int k = k0 + i;
    float x;
    if (l == 0) x = (k < KX) ? Wih0[g * 64 + k] : Whh[g * 256 + (k - KX)];
    else        x = (k < KX) ? Wih[(size_t)((l - 1) * 1024 + g) * 256 + k]
                             : Whh[(size_t)(l * 1024 + g) * 256 + (k - KX)];
    v[i] = x;
  }
  u32 pk[4];
#pragma unroll
  for (int i = 0; i < 4; ++i)
    pk[i] = (u32)f2h(v[2 * i]) | ((u32)f2h(v[2 * i + 1]) << 16);
  uint4 val; val.x = pk[0]; val.y = pk[1]; val.z = pk[2]; val.w = pk[3];
  u16* dst = wf + (size_t)l * WF_LAYER_ELEMS + ((size_t)(gnt * NKC + kc) * 64 + lane) * 8;
  *(uint4*)dst = val;
}

// ---------------- LSTM layer v7 ----------------
// One block = 16 batch rows, 1024 threads = 16 waves = 4 gates x 2 nt-halves x 2 K-halves.
// Wave (w, nh, kh): gate w, nt in [nh*8, nh*8+8), kc in [kh*KCL, (kh+1)*KCL).
// A = [x_t ; h_{t-1}] 16 x K fp16 in LDS (row stride 1024B, XOR swizzle (row&7)<<4).
// W streamed from L2/HBM (compiler-scheduled per-nt batches); 4 waves/SIMD hide latency.
// Partial sums over kh reduced through glds in phase 3.
template <int NKC, int KCL, int KX, bool L0>
__global__ __launch_bounds__(1024, 4) void lstm_layer_v7(
    const float* __restrict__ X,      // only for L0
    u16* __restrict__ seq,            // [NBLK][T][16][256] fp16, in-place x->h
    const u16* __restrict__ wf,       // this layer's packed weights
    const float* __restrict__ bias)   // [1024]
{
  __shared__ __align__(16) u16  Ahi[16 * 512];        // 16 KiB (rows at 1024 B stride)
  __shared__ float glds[2][4][16][260];               // 130 KiB partial-sum buffers

  const int tid  = threadIdx.x;
  const int wid  = tid >> 6;           // 0..15
  const int w    = wid & 3;            // gate
  const int nh   = (wid >> 2) & 1;     // nt-half
  const int kh   = wid >> 3;           // K-half
  const int lane = tid & 63;
  const int bid  = blockIdx.x;
  const int arow = lane & 15;          // A row / D col within MFMA
  const int ahi  = lane >> 4;          // k-group / D row-group
  const int aswz = (arow & 7) << 4;
  const int kc0  = kh * KCL;
  const int nt0  = nh * 8;

  // zero all of A once (16 rows x 1024 B); x-part overwritten each t, h-part by phase 3
  {
    int r = tid >> 6, o = (tid & 63) * 16;
    uint4 z; z.x = z.y = z.z = z.w = 0;
    *(uint4*)((char*)Ahi + r * 1024 + o) = z;
  }

  // phase-3 state: thread owns col j = tid&255, rows rh*4 .. rh*4+3
  const int j  = tid & 255;
  const int rh = tid >> 8;
  float c[4];
#pragma unroll
  for (int q = 0; q < 4; ++q) c[q] = 0.f;

  float bv[8];
  if (kh == 0) {
#pragma unroll
    for (int i = 0; i < 8; ++i) bv[i] = bias[w * 256 + (nt0 + i) * 16 + arow];
  }

  // W base for this wave: fragment (gnt = w*16+nt, kc = kc0+i) at
  // wf[((gnt*NKC + kc)*64 + lane)*8]
  const u16* wb = wf + ((size_t)(w * 16) * NKC + kc0) * 512 + (size_t)lane * 8;

  for (int t = 0; t < T_; ++t) {
    // ---- phase 1: load x_t into A (swizzled) ----
    if constexpr (L0) {
      int r = tid >> 6, k = tid & 63;
      float xv = X[((size_t)(bid * 16 + r) * T_ + t) * D_ + k];
      *(u16*)((char*)Ahi + r * 1024 + ((k * 2) ^ ((r & 7) << 4))) = f2h(xv);
    } else {
      int r = tid >> 6, seg = tid & 63;
      uint2 v = *(const uint2*)(seq + ((((size_t)bid * T_ + t) * 16 + r) << 8) + seg * 4);
      *(uint2*)((char*)Ahi + r * 1024 + ((seg * 8) ^ ((r & 7) << 4))) = v;
    }
    __syncthreads();

    // ---- phase 2: partial gates = A[:, kc0..kc0+KCL) @ W^T (+bias for kh=0) ----
    v8hf a[KCL];
#pragma unroll
    for (int i = 0; i < KCL; ++i)
      a[i] = *(const v8hf*)((const char*)Ahi + arow * 1024 + (((kc0 + i) * 64 + ahi * 16) ^ aswz));

#pragma unroll
    for (int i2 = 0; i2 < 8; ++i2) {
      const int nt = nt0 + i2;
      v8hf bf[KCL];
#pragma unroll
      for (int i = 0; i < KCL; ++i)
        bf[i] = *(const v8hf*)(const void*)(wb + (size_t)(nt * NKC + i) * 512);
      f32x4 acc;
      if (kh == 0) { acc[0] = bv[i2]; acc[1] = bv[i2]; acc[2] = bv[i2]; acc[3] = bv[i2]; }
      else         { acc[0] = 0.f;    acc[1] = 0.f;    acc[2] = 0.f;    acc[3] = 0.f;    }
#pragma unroll
      for (int i = 0; i < KCL; ++i)
        acc = __builtin_amdgcn_mfma_f32_16x16x32_f16(a[i], bf[i], acc, 0, 0, 0);
#pragma unroll
      for (int q = 0; q < 4; ++q)
        glds[kh][w][ahi * 4 + q][nt * 16 + arow] = acc[q];  // D: row=(lane>>4)*4+q, col=lane&15
    }
    __syncthreads();

    // ---- phase 3: reduce K-halves + nonlinearity + state update ----
    u16* srow = seq + ((((size_t)bid * T_ + t) * 16) << 8) + j;
#pragma unroll
    for (int q = 0; q < 4; ++q) {
      int r = rh * 4 + q;
      float iv = glds[0][0][r][j] + glds[1][0][r][j];
      float fv = glds[0][1][r][j] + glds[1][1][r][j];
      float gv = glds[0][2][r][j] + glds[1][2][r][j];
      float ov = glds[0][3][r][j] + glds[1][3][r][j];
      float cn = fsig(fv) * c[q] + fsig(iv) * ftanh(gv);
      c[q] = cn;
      float h = fsig(ov) * ftanh(cn);
      u16 hb = f2h(h);
      srow[(size_t)r << 8] = hb;                             // global (next layer / tail)
      *(u16*)((char*)Ahi + r * 1024 + (((KX + j) * 2) ^ ((r & 7) << 4))) = hb;  // A h-part
    }
    // next phase-1 writes the x-part (disjoint from h-part); the barrier after
    // phase 1 orders phase-3 LDS/global effects before phase 2 of t+1.
  }
}

// ---------------- tail (encoder / sample / decoder) ----------------
template <int N, int K, bool RELU>
__device__ __forceinline__ void dense(const float (*__restrict__ in)[512],
                                      float (*__restrict__ out)[512],
                                      const float* __restrict__ W,
                                      const float* __restrict__ bg, int tid) {
  for (int e = tid; e < 16 * N; e += 256) {
    int r = e / N, n = e - r * N;
    const float* wr = W + (size_t)n * K;
    const float* ar = in[r];
    float4 acc = {0.f, 0.f, 0.f, 0.f};
    for (int k = 0; k < K; k += 4) {
      float4 wv = *(const float4*)(wr + k);
      float4 av = *(const float4*)(ar + k);
      acc.x = fmaf(wv.x, av.x, acc.x);
      acc.y = fmaf(wv.y, av.y, acc.y);
      acc.z = fmaf(wv.z, av.z, acc.z);
      acc.w = fmaf(wv.w, av.w, acc.w);
    }
    float s = bg[n] + acc.x + acc.y + acc.z + acc.w;
    out[r][n] = RELU ? fmaxf(s, 0.f) : s;
  }
}

template <int K>
__device__ __forceinline__ float dotK(const float* __restrict__ a, const float* __restrict__ w) {
  float4 acc = {0.f, 0.f, 0.f, 0.f};
#pragma unroll
  for (int k = 0; k < K; k += 4) {
    float4 wv = *(const float4*)(w + k);
    float4 av = *(const float4*)(a + k);
    acc.x = fmaf(wv.x, av.x, acc.x);
    acc.y = fmaf(wv.y, av.y, acc.y);
    acc.z = fmaf(wv.z, av.z, acc.z);
    acc.w = fmaf(wv.w, av.w, acc.w);
  }
  return acc.x + acc.y + acc.z + acc.w;
}

struct TailArgs {
  const u16* seq;
  const float *ef1w, *ef1b, *ef2w, *ef2b;
  const float *mean_w, *mean_b, *logvar_w, *logvar_b;
  const float *scale_w, *scale_b, *shape_w, *shape_b;
  const float *df1w, *df1b, *df2w, *df2b, *outw, *outb, *finw, *finb;
  const float *pi, *eps, *u, *choice;
  float* out;
};

__global__ __launch_bounds__(256) void tail_kernel_v7(TailArgs A) {
  __shared__ float a0[16][512];
  __shared__ float a1[16][512];
  const int tid = threadIdx.x, bid = blockIdx.x;

  // last hidden state (t = T-1) of final layer
  for (int e = tid; e < 16 * 256; e += 256) {
    int r = e >> 8, jj = e & 255;
    a0[r][jj] = h2f(A.seq[((((size_t)bid * T_ + (T_ - 1)) * 16 + r) << 8) + jj]);
  }
  __syncthreads();

  dense<128, 256, true>(a0, a1, A.ef1w, A.ef1b, tid); __syncthreads();
  dense<64, 128, true>(a1, a0, A.ef2w, A.ef2b, tid);  __syncthreads();

  // heads + reparameterization / GPD mixture
  const float pi = *A.pi;
  for (int e = tid; e < 16 * 64; e += 256) {
    int r = e >> 6, n = e & 63;
    size_t rg = (size_t)bid * 16 + r;
    float m  = dotK<64>(a0[r], A.mean_w   + n * 64) + A.mean_b[n];
    float lv = dotK<64>(a0[r], A.logvar_w + n * 64) + A.logvar_b[n];
    float sc = __expf(dotK<64>(a0[r], A.scale_w + n * 64) + A.scale_b[n]);
    float sh = dotK<64>(a0[r], A.shape_w + n * 64) + A.shape_b[n];
    A.out[196608 + rg * 64 + n] = m;    // z_mean
    A.out[327680 + rg * 64 + n] = lv;   // z_logvar
    A.out[458752 + rg * 64 + n] = sc;   // z_scale
    A.out[589824 + rg * 64 + n] = sh;   // z_shape
    float zg = m + A.eps[rg * 64 + n] * __expf(0.5f * lv);
    float L  = log1pf(-A.u[rg * 64 + n]);
    float zp = sc / sh * (__expf(-sh * L) - 1.f);
    a1[r][n] = (A.choice[rg] < pi) ? zg : zp;
  }
  __syncthreads();

  dense<128, 64, true>(a1, a0, A.df1w, A.df1b, tid);   __syncthreads();
  dense<500, 128, true>(a0, a1, A.df2w, A.df2b, tid);  __syncthreads();
  dense<96, 500, false>(a1, a0, A.outw, A.outb, tid);  __syncthreads();
  dense<96, 96, false>(a0, a1, A.finw, A.finb, tid);   __syncthreads();

  for (int e = tid; e < 16 * FUT_; e += 256) {
    int r = e / FUT_, n = e - r * FUT_;
    A.out[((size_t)bid * 16 + r) * FUT_ + n] = a1[r][n];
  }
}

// ---------------- launch ----------------
extern "C" void kernel_launch(void* const* d_in, const int* in_sizes, int n_in,
                              void* d_out, int out_size, void* d_ws, size_t ws_size,
                              hipStream_t stream) {
  (void)in_sizes; (void)n_in; (void)out_size; (void)ws_size;

  const float* X      = (const float*)d_in[0];
  const float* Wih0   = (const float*)d_in[1];
  const float* Wih    = (const float*)d_in[2];
  const float* Whh    = (const float*)d_in[3];
  const float* b      = (const float*)d_in[4];
  const float* ef1w   = (const float*)d_in[5];
  const float* ef1b   = (const float*)d_in[6];
  const float* ef2w   = (const float*)d_in[7];
  const float* ef2b   = (const float*)d_in[8];
  const float* mean_w = (const float*)d_in[9];
  const float* mean_b = (const float*)d_in[10];
  const float* logvar_w = (const float*)d_in[11];
  const float* logvar_b = (const float*)d_in[12];
  const float* scale_w  = (const float*)d_in[13];
  const float* scale_b  = (const float*)d_in[14];
  const float* shape_w  = (const float*)d_in[15];
  const float* shape_b  = (const float*)d_in[16];
  const float* df1w   = (const float*)d_in[17];
  const float* df1b   = (const float*)d_in[18];
  const float* df2w   = (const float*)d_in[19];
  const float* df2b   = (const float*)d_in[20];
  const float* outw   = (const float*)d_in[21];
  const float* outb   = (const float*)d_in[22];
  const float* finw   = (const float*)d_in[23];
  const float* finb   = (const float*)d_in[24];
  const float* pi_g   = (const float*)d_in[25];
  const float* eps    = (const float*)d_in[26];
  const float* u      = (const float*)d_in[27];
  const float* choice = (const float*)d_in[28];

  u16* wf  = (u16*)d_ws;
  u16* seq = (u16*)((char*)d_ws + SEQ_OFF);
  float* out = (float*)d_out;

  pack_weights_v7<<<2560, 256, 0, stream>>>(Wih0, Wih, Whh, wf);

  // LSTM stack (in-place on seq; layer 0 reads X)
  lstm_layer_v7<10, 5, 64, true><<<NBLK, 1024, 0, stream>>>(X, seq, wf, b);
  for (int l = 1; l < NL_; ++l)
    lstm_layer_v7<16, 8, 256, false><<<NBLK, 1024, 0, stream>>>(nullptr, seq,
        wf + (size_t)l * WF_LAYER_ELEMS, b + l * 1024);

  TailArgs A;
  A.seq = seq;
  A.ef1w = ef1w; A.ef1b = ef1b; A.ef2w = ef2w; A.ef2b = ef2b;
  A.mean_w = mean_w; A.mean_b = mean_b; A.logvar_w = logvar_w; A.logvar_b = logvar_b;
  A.scale_w = scale_w; A.scale_b = scale_b; A.shape_w = shape_w; A.shape_b = shape_b;
  A.df1w = df1w; A.df1b = df1b; A.df2w = df2w; A.df2b = df2b;
  A.outw = outw; A.outb = outb; A.finw = finw; A.finb = finb;
  A.pi = pi_g; A.eps = eps; A.u = u; A.choice = choice;
  A.out = out;
  tail_kernel_v7<<<NBLK, 256, 0, stream>>>(A);
}

// Round 10
// 12583.923 us; speedup vs baseline: 1.8919x; 1.4686x over previous
//
#include <hip/hip_runtime.h>

typedef unsigned short u16;
typedef unsigned int   u32;
typedef _Float16 v8hf __attribute__((ext_vector_type(8)));
typedef float  f32x4 __attribute__((ext_vector_type(4)));

// ---------------- problem constants ----------------
static constexpr int B_   = 2048;
static constexpr int T_   = 64;
static constexpr int D_   = 64;
static constexpr int H_   = 256;
static constexpr int NL_  = 10;
static constexpr int FUT_ = 96;
static constexpr int NBLK = 128;     // B/16

// workspace layout (bytes)
static constexpr size_t WF_LAYER_ELEMS = 524288;          // u16 per layer (1 MiB slot)
static constexpr size_t SEQ_OFF        = 16u << 20;       // seq buffer at +16 MiB
// seq: fp16 [NBLK][T][16][256]  = 64 MiB

// ---------------- small helpers ----------------
__device__ __forceinline__ u16 f2h(float f) {
  _Float16 h = (_Float16)f;                 // RNE v_cvt_f16_f32
  return __builtin_bit_cast(u16, h);
}
__device__ __forceinline__ float h2f(u16 b) {
  return (float)__builtin_bit_cast(_Float16, b);
}
__device__ __forceinline__ float rcp_(float x) { return __builtin_amdgcn_rcpf(x); }
__device__ __forceinline__ float fsig(float x) { return rcp_(1.f + __expf(-x)); }
__device__ __forceinline__ float ftanh(float x) {
  float e = __expf(-2.f * fabsf(x));
  float t = (1.f - e) * rcp_(1.f + e);
  return copysignf(t, x);
}

// async global -> LDS DMA, 16 B per lane; LDS dest = wave-uniform base + lane*16,
// global src = per-lane address (rule 21: both sides linear).
__device__ __forceinline__ void gld16(const u16* g, u16* l) {
  __builtin_amdgcn_global_load_lds(
      (const __attribute__((address_space(1))) void*)g,
      (__attribute__((address_space(3))) void*)l,
      16, 0, 0);
}

// ---------------- weight packing (fp16 B-fragment order, [kc][cg][gate]) ----------------
// Fragment (kc, cg, g): element (lane, i) =
//   Wcat[row = g*256 + cg*16 + (lane&15)][k = kc*32 + (lane>>4)*8 + i]
// stored at wf[l*WF + ((kc*16 + cg)*4 + g)*512 + lane*8 + i]
// -> per (kc, wave=cg) slice of 4 gates is one contiguous 4 KiB block.
__global__ void pack_weights_v8(const float* __restrict__ Wih0,
                                const float* __restrict__ Wih,
                                const float* __restrict__ Whh,
                                u16* __restrict__ wf) {
  int gid = blockIdx.x * 256 + threadIdx.x;
  int l   = gid >> 16;            // 65536 frag-threads per layer
  if (l >= NL_) return;
  int rem  = gid & 65535;
  int kc   = rem >> 12;           // 0..15
  int cg   = (rem >> 8) & 15;     // 0..15
  int g    = (rem >> 6) & 3;      // 0..3
  int lane = rem & 63;
  const int NKC = (l == 0) ? 10 : 16;
  if (kc >= NKC) return;
  const int KX = (l == 0) ? 64 : 256;

  int row = g * 256 + cg * 16 + (lane & 15);
  int k0  = kc * 32 + (lane >> 4) * 8;

  float v[8];
#pragma unroll
  for (int i = 0; i < 8; ++i) {
    int k = k0 + i;
    float x;
    if (l == 0) x = (k < KX) ? Wih0[row * 64 + k] : Whh[row * 256 + (k - KX)];
    else        x = (k < KX) ? Wih[(size_t)((l - 1) * 1024 + row) * 256 + k]
                             : Whh[(size_t)(l * 1024 + row) * 256 + (k - KX)];
    v[i] = x;
  }
  u32 pk[4];
#pragma unroll
  for (int i = 0; i < 4; ++i)
    pk[i] = (u32)f2h(v[2 * i]) | ((u32)f2h(v[2 * i + 1]) << 16);
  uint4 val; val.x = pk[0]; val.y = pk[1]; val.z = pk[2]; val.w = pk[3];
  u16* dst = wf + (size_t)l * WF_LAYER_ELEMS
                + ((size_t)(kc * 16 + cg) * 4 + g) * 512 + (size_t)lane * 8;
  *(uint4*)dst = val;
}

// ---------------- LSTM layer v8 ----------------
// One block = 16 batch rows, 1024 threads = 16 waves; wave wid owns h-columns
// [wid*16, wid*16+16) x ALL FOUR gates, full K. Gates accumulate in registers
// (no glds). W streamed via async global_load_lds into a 2 x 64 KiB LDS double
// buffer (wave-private 4 KiB slices), counted vmcnt(4) -- never drained mid-loop.
// A = [x_t ; h_{t-1}] 16 x K fp16 in LDS (row stride 1024 B, XOR swizzle (r&7)<<4).
template <int NKC, int KX, bool L0>
__global__ __launch_bounds__(1024, 4) void lstm_layer_v8(
    const float* __restrict__ X,      // only for L0
    u16* __restrict__ seq,            // [NBLK][T][16][256] fp16, in-place x->h
    const u16* __restrict__ wf,       // this layer's packed weights
    const float* __restrict__ bias)   // [1024]
{
  __shared__ __align__(16) u16 Albs[16 * 512];      // 16 KiB
  __shared__ __align__(16) u16 Wbuf[2][32768];      // 2 x 64 KiB W stream buffers

  const int tid  = threadIdx.x;
  const int wid  = tid >> 6;           // wave = column-group cg (0..15)
  const int lane = tid & 63;
  const int bid  = blockIdx.x;
  const int arow = lane & 15;          // A row / D col within MFMA
  const int ahi  = lane >> 4;
  const int aswz = (arow & 7) << 4;
  const int j    = wid * 16 + arow;    // h column this lane owns

  // zero all of A (h-part needed zero at t=0; x-part overwritten each t)
  {
    int r = tid >> 6, o = (tid & 63) * 16;
    uint4 z; z.x = z.y = z.z = z.w = 0;
    *(uint4*)((char*)Albs + r * 1024 + o) = z;
  }

  float c[4] = {0.f, 0.f, 0.f, 0.f};   // cell state: rows ahi*4+q, col j
  float bv[4];
#pragma unroll
  for (int g = 0; g < 4; ++g) bv[g] = bias[g * 256 + j];

  // per-lane global src base for this wave's W slices: + kc*32768 + g*512
  const u16* wsrc = wf + (size_t)wid * 2048 + (size_t)lane * 8;
  // wave-uniform LDS dest bases
  u16* wdst0 = &Wbuf[0][wid * 2048];
  u16* wdst1 = &Wbuf[1][wid * 2048];

  // stage kc=0 for t=0
#pragma unroll
  for (int g = 0; g < 4; ++g) gld16(wsrc + g * 512, wdst0 + g * 512);

  for (int t = 0; t < T_; ++t) {
    // ---- phase 1: load x_t into A (swizzled) ----
    if constexpr (L0) {
      int r = tid >> 6, k = tid & 63;
      float xv = X[((size_t)(bid * 16 + r) * T_ + t) * D_ + k];
      *(u16*)((char*)Albs + r * 1024 + ((k * 2) ^ ((r & 7) << 4))) = f2h(xv);
    } else {
      int r = tid >> 6, seg = tid & 63;
      uint2 v = *(const uint2*)(seq + ((((size_t)bid * T_ + t) * 16 + r) << 8) + seg * 4);
      *(uint2*)((char*)Albs + r * 1024 + ((seg * 8) ^ ((r & 7) << 4))) = v;
    }
    __syncthreads();   // A ready; drains all vmem (kc=0 stage complete, count = 0)

    // ---- phase 2: full-K gates for this wave's 16 columns, acc in registers ----
    f32x4 acc[4];
#pragma unroll
    for (int g = 0; g < 4; ++g) {
      acc[g][0] = bv[g]; acc[g][1] = bv[g]; acc[g][2] = bv[g]; acc[g][3] = bv[g];
    }

#pragma unroll
    for (int kc = 0; kc < NKC; ++kc) {
      if (kc + 1 < NKC) {
        // stage next slice into the other buffer (wave-private; no barrier needed)
        u16* nd = ((kc + 1) & 1) ? wdst1 : wdst0;
#pragma unroll
        for (int g = 0; g < 4; ++g)
          gld16(wsrc + (size_t)(kc + 1) * 32768 + g * 512, nd + g * 512);
        asm volatile("s_waitcnt vmcnt(4)" ::: "memory");   // kc's slice landed
      } else {
        asm volatile("s_waitcnt vmcnt(0)" ::: "memory");
      }
      __builtin_amdgcn_sched_barrier(0);                   // rule 18 fence

      v8hf a = *(const v8hf*)((const char*)Albs + arow * 1024 +
                              ((kc * 64 + ahi * 16) ^ aswz));
      const u16* wl = ((kc & 1) ? wdst1 : wdst0) + lane * 8;
#pragma unroll
      for (int g = 0; g < 4; ++g) {
        v8hf bw = *(const v8hf*)(const void*)(wl + g * 512);
        acc[g] = __builtin_amdgcn_mfma_f32_16x16x32_f16(a, bw, acc[g], 0, 0, 0);
      }
    }
    __syncthreads();   // all waves done reading A before h-part is overwritten

    // stage kc=0 for t+1 now -- latency hides under phase 3 + next phase 1
    __builtin_amdgcn_sched_barrier(0);
#pragma unroll
    for (int g = 0; g < 4; ++g) gld16(wsrc + g * 512, wdst0 + g * 512);

    // ---- phase 3: nonlinearity + state update, fully in-register ----
    // D layout: col = lane&15 (= j), row = ahi*4 + q  [m89 mapping]
    u16* sbase = seq + ((((size_t)bid * T_ + t) * 16) << 8) + j;
#pragma unroll
    for (int q = 0; q < 4; ++q) {
      int r = ahi * 4 + q;
      float cn = fsig(acc[1][q]) * c[q] + fsig(acc[0][q]) * ftanh(acc[2][q]);
      c[q] = cn;
      float h = fsig(acc[3][q]) * ftanh(cn);
      u16 hb = f2h(h);
      sbase[(size_t)r << 8] = hb;                                           // global seq
      *(u16*)((char*)Albs + r * 1024 + (((KX + j) * 2) ^ ((r & 7) << 4))) = hb;  // A h-part
    }
    // next phase-1 writes the x-part (disjoint); its barrier orders everything.
  }
}

// ---------------- tail (encoder / sample / decoder) ----------------
template <int N, int K, bool RELU>
__device__ __forceinline__ void dense(const float (*__restrict__ in)[512],
                                      float (*__restrict__ out)[512],
                                      const float* __restrict__ W,
                                      const float* __restrict__ bg, int tid) {
  for (int e = tid; e < 16 * N; e += 256) {
    int r = e / N, n = e - r * N;
    const float* wr = W + (size_t)n * K;
    const float* ar = in[r];
    float4 acc = {0.f, 0.f, 0.f, 0.f};
    for (int k = 0; k < K; k += 4) {
      float4 wv = *(const float4*)(wr + k);
      float4 av = *(const float4*)(ar + k);
      acc.x = fmaf(wv.x, av.x, acc.x);
      acc.y = fmaf(wv.y, av.y, acc.y);
      acc.z = fmaf(wv.z, av.z, acc.z);
      acc.w = fmaf(wv.w, av.w, acc.w);
    }
    float s = bg[n] + acc.x + acc.y + acc.z + acc.w;
    out[r][n] = RELU ? fmaxf(s, 0.f) : s;
  }
}

template <int K>
__device__ __forceinline__ float dotK(const float* __restrict__ a, const float* __restrict__ w) {
  float4 acc = {0.f, 0.f, 0.f, 0.f};
#pragma unroll
  for (int k = 0; k < K; k += 4) {
    float4 wv = *(const float4*)(w + k);
    float4 av = *(const float4*)(a + k);
    acc.x = fmaf(wv.x, av.x, acc.x);
    acc.y = fmaf(wv.y, av.y, acc.y);
    acc.z = fmaf(wv.z, av.z, acc.z);
    acc.w = fmaf(wv.w, av.w, acc.w);
  }
  return acc.x + acc.y + acc.z + acc.w;
}

struct TailArgs {
  const u16* seq;
  const float *ef1w, *ef1b, *ef2w, *ef2b;
  const float *mean_w, *mean_b, *logvar_w, *logvar_b;
  const float *scale_w, *scale_b, *shape_w, *shape_b;
  const float *df1w, *df1b, *df2w, *df2b, *outw, *outb, *finw, *finb;
  const float *pi, *eps, *u, *choice;
  float* out;
};

__global__ __launch_bounds__(256) void tail_kernel_v8(TailArgs A) {
  __shared__ float a0[16][512];
  __shared__ float a1[16][512];
  const int tid = threadIdx.x, bid = blockIdx.x;

  // last hidden state (t = T-1) of final layer
  for (int e = tid; e < 16 * 256; e += 256) {
    int r = e >> 8, jj = e & 255;
    a0[r][jj] = h2f(A.seq[((((size_t)bid * T_ + (T_ - 1)) * 16 + r) << 8) + jj]);
  }
  __syncthreads();

  dense<128, 256, true>(a0, a1, A.ef1w, A.ef1b, tid); __syncthreads();
  dense<64, 128, true>(a1, a0, A.ef2w, A.ef2b, tid);  __syncthreads();

  // heads + reparameterization / GPD mixture
  const float pi = *A.pi;
  for (int e = tid; e < 16 * 64; e += 256) {
    int r = e >> 6, n = e & 63;
    size_t rg = (size_t)bid * 16 + r;
    float m  = dotK<64>(a0[r], A.mean_w   + n * 64) + A.mean_b[n];
    float lv = dotK<64>(a0[r], A.logvar_w + n * 64) + A.logvar_b[n];
    float sc = __expf(dotK<64>(a0[r], A.scale_w + n * 64) + A.scale_b[n]);
    float sh = dotK<64>(a0[r], A.shape_w + n * 64) + A.shape_b[n];
    A.out[196608 + rg * 64 + n] = m;    // z_mean
    A.out[327680 + rg * 64 + n] = lv;   // z_logvar
    A.out[458752 + rg * 64 + n] = sc;   // z_scale
    A.out[589824 + rg * 64 + n] = sh;   // z_shape
    float zg = m + A.eps[rg * 64 + n] * __expf(0.5f * lv);
    float L  = log1pf(-A.u[rg * 64 + n]);
    float zp = sc / sh * (__expf(-sh * L) - 1.f);
    a1[r][n] = (A.choice[rg] < pi) ? zg : zp;
  }
  __syncthreads();

  dense<128, 64, true>(a1, a0, A.df1w, A.df1b, tid);   __syncthreads();
  dense<500, 128, true>(a0, a1, A.df2w, A.df2b, tid);  __syncthreads();
  dense<96, 500, false>(a1, a0, A.outw, A.outb, tid);  __syncthreads();
  dense<96, 96, false>(a0, a1, A.finw, A.finb, tid);   __syncthreads();

  for (int e = tid; e < 16 * FUT_; e += 256) {
    int r = e / FUT_, n = e - r * FUT_;
    A.out[((size_t)bid * 16 + r) * FUT_ + n] = a1[r][n];
  }
}

// ---------------- launch ----------------
extern "C" void kernel_launch(void* const* d_in, const int* in_sizes, int n_in,
                              void* d_out, int out_size, void* d_ws, size_t ws_size,
                              hipStream_t stream) {
  (void)in_sizes; (void)n_in; (void)out_size; (void)ws_size;

  const float* X      = (const float*)d_in[0];
  const float* Wih0   = (const float*)d_in[1];
  const float* Wih    = (const float*)d_in[2];
  const float* Whh    = (const float*)d_in[3];
  const float* b      = (const float*)d_in[4];
  const float* ef1w   = (const float*)d_in[5];
  const float* ef1b   = (const float*)d_in[6];
  const float* ef2w   = (const float*)d_in[7];
  const float* ef2b   = (const float*)d_in[8];
  const float* mean_w = (const float*)d_in[9];
  const float* mean_b = (const float*)d_in[10];
  const float* logvar_w = (const float*)d_in[11];
  const float* logvar_b = (const float*)d_in[12];
  const float* scale_w  = (const float*)d_in[13];
  const float* scale_b  = (const float*)d_in[14];
  const float* shape_w  = (const float*)d_in[15];
  const float* shape_b  = (const float*)d_in[16];
  const float* df1w   = (const float*)d_in[17];
  const float* df1b   = (const float*)d_in[18];
  const float* df2w   = (const float*)d_in[19];
  const float* df2b   = (const float*)d_in[20];
  const float* outw   = (const float*)d_in[21];
  const float* outb   = (const float*)d_in[22];
  const float* finw   = (const float*)d_in[23];
  const float* finb   = (const float*)d_in[24];
  const float* pi_g   = (const float*)d_in[25];
  const float* eps    = (const float*)d_in[26];
  const float* u      = (const float*)d_in[27];
  const float* choice = (const float*)d_in[28];

  u16* wf  = (u16*)d_ws;
  u16* seq = (u16*)((char*)d_ws + SEQ_OFF);
  float* out = (float*)d_out;

  pack_weights_v8<<<2560, 256, 0, stream>>>(Wih0, Wih, Whh, wf);

  // LSTM stack (in-place on seq; layer 0 reads X)
  lstm_layer_v8<10, 64, true><<<NBLK, 1024, 0, stream>>>(X, seq, wf, b);
  for (int l = 1; l < NL_; ++l)
    lstm_layer_v8<16, 256, false><<<NBLK, 1024, 0, stream>>>(nullptr, seq,
        wf + (size_t)l * WF_LAYER_ELEMS, b + l * 1024);

  TailArgs A;
  A.seq = seq;
  A.ef1w = ef1w; A.ef1b = ef1b; A.ef2w = ef2w; A.ef2b = ef2b;
  A.mean_w = mean_w; A.mean_b = mean_b; A.logvar_w = logvar_w; A.logvar_b = logvar_b;
  A.scale_w = scale_w; A.scale_b = scale_b; A.shape_w = shape_w; A.shape_b = shape_b;
  A.df1w = df1w; A.df1b = df1b; A.df2w = df2w; A.df2b = df2b;
  A.outw = outw; A.outb = outb; A.finw = finw; A.finb = finb;
  A.pi = pi_g; A.eps = eps; A.u = u; A.choice = choice;
  A.out = out;
  tail_kernel_v8<<<NBLK, 256, 0, stream>>>(A);
}

// Round 11
// 10669.922 us; speedup vs baseline: 2.2313x; 1.1794x over previous
//
#include <hip/hip_runtime.h>

typedef unsigned short u16;
typedef unsigned int   u32;
typedef _Float16 v8hf __attribute__((ext_vector_type(8)));
typedef float  f32x4 __attribute__((ext_vector_type(4)));

// ---------------- problem constants ----------------
static constexpr int B_   = 2048;
static constexpr int T_   = 64;
static constexpr int D_   = 64;
static constexpr int H_   = 256;
static constexpr int NL_  = 10;
static constexpr int FUT_ = 96;
static constexpr int NBLK = 128;     // B/16

// ---- old (v8 fallback) workspace layout ----
static constexpr size_t WF_LAYER_ELEMS = 524288;          // u16 per layer (1 MiB slot)
static constexpr size_t SEQ_OFF        = 16u << 20;       // seq at +16 MiB (v8 path)

// ---- new (v9) workspace layout (bytes) ----
static constexpr size_t WFH_OFF  = 0;                     // Whh frags: 10 x 512 KiB
static constexpr size_t WFX_OFF  = 5u << 20;              // Wih frags: 10 x 512 KiB slots
static constexpr size_t XG_OFF   = 10u << 20;             // xg ring: 128 blk x 128 KiB = 16 MiB
static constexpr size_t SEQ2_OFF = 26u << 20;             // seq: 64 MiB
static constexpr size_t WS_NEED_V9 = SEQ2_OFF + (64ull << 20);   // 90 MiB
static constexpr int    WFL9 = 262144;                    // u16 per layer frag slot (8*16*4*512)
static constexpr int    TCH  = 4;                         // timesteps per chunk

// ---------------- small helpers ----------------
__device__ __forceinline__ u16 f2h(float f) {
  _Float16 h = (_Float16)f;                 // RNE v_cvt_f16_f32
  return __builtin_bit_cast(u16, h);
}
__device__ __forceinline__ float h2f(u16 b) {
  return (float)__builtin_bit_cast(_Float16, b);
}
__device__ __forceinline__ float rcp_(float x) { return __builtin_amdgcn_rcpf(x); }
__device__ __forceinline__ float fsig(float x) { return rcp_(1.f + __expf(-x)); }
__device__ __forceinline__ float ftanh(float x) {
  float e = __expf(-2.f * fabsf(x));
  float t = (1.f - e) * rcp_(1.f + e);
  return copysignf(t, x);
}
__device__ __forceinline__ void gld16(const u16* g, u16* l) {
  __builtin_amdgcn_global_load_lds(
      (const __attribute__((address_space(1))) void*)g,
      (__attribute__((address_space(3))) void*)l,
      16, 0, 0);
}

// =====================================================================
// ===================  v8 path (verified fallback)  ===================
// =====================================================================
__global__ void pack_weights_v8(const float* __restrict__ Wih0,
                                const float* __restrict__ Wih,
                                const float* __restrict__ Whh,
                                u16* __restrict__ wf) {
  int gid = blockIdx.x * 256 + threadIdx.x;
  int l   = gid >> 16;
  if (l >= NL_) return;
  int rem  = gid & 65535;
  int kc   = rem >> 12;
  int cg   = (rem >> 8) & 15;
  int g    = (rem >> 6) & 3;
  int lane = rem & 63;
  const int NKC = (l == 0) ? 10 : 16;
  if (kc >= NKC) return;
  const int KX = (l == 0) ? 64 : 256;

  int row = g * 256 + cg * 16 + (lane & 15);
  int k0  = kc * 32 + (lane >> 4) * 8;

  float v[8];
#pragma unroll
  for (int i = 0; i < 8; ++i) {
    int k = k0 + i;
    float x;
    if (l == 0) x = (k < KX) ? Wih0[row * 64 + k] : Whh[row * 256 + (k - KX)];
    else        x = (k < KX) ? Wih[(size_t)((l - 1) * 1024 + row) * 256 + k]
                             : Whh[(size_t)(l * 1024 + row) * 256 + (k - KX)];
    v[i] = x;
  }
  u32 pk[4];
#pragma unroll
  for (int i = 0; i < 4; ++i)
    pk[i] = (u32)f2h(v[2 * i]) | ((u32)f2h(v[2 * i + 1]) << 16);
  uint4 val; val.x = pk[0]; val.y = pk[1]; val.z = pk[2]; val.w = pk[3];
  u16* dst = wf + (size_t)l * WF_LAYER_ELEMS
                + ((size_t)(kc * 16 + cg) * 4 + g) * 512 + (size_t)lane * 8;
  *(uint4*)dst = val;
}

template <int NKC, int KX, bool L0>
__global__ __launch_bounds__(1024, 4) void lstm_layer_v8(
    const float* __restrict__ X,
    u16* __restrict__ seq,
    const u16* __restrict__ wf,
    const float* __restrict__ bias) {
  __shared__ __align__(16) u16 Albs[16 * 512];
  __shared__ __align__(16) u16 Wbuf[2][32768];

  const int tid  = threadIdx.x;
  const int wid  = tid >> 6;
  const int lane = tid & 63;
  const int bid  = blockIdx.x;
  const int arow = lane & 15;
  const int ahi  = lane >> 4;
  const int aswz = (arow & 7) << 4;
  const int j    = wid * 16 + arow;

  {
    int r = tid >> 6, o = (tid & 63) * 16;
    uint4 z; z.x = z.y = z.z = z.w = 0;
    *(uint4*)((char*)Albs + r * 1024 + o) = z;
  }

  float c[4] = {0.f, 0.f, 0.f, 0.f};
  float bv[4];
#pragma unroll
  for (int g = 0; g < 4; ++g) bv[g] = bias[g * 256 + j];

  const u16* wsrc = wf + (size_t)wid * 2048 + (size_t)lane * 8;
  u16* wdst0 = &Wbuf[0][wid * 2048];
  u16* wdst1 = &Wbuf[1][wid * 2048];

#pragma unroll
  for (int g = 0; g < 4; ++g) gld16(wsrc + g * 512, wdst0 + g * 512);

  for (int t = 0; t < T_; ++t) {
    if constexpr (L0) {
      int r = tid >> 6, k = tid & 63;
      float xv = X[((size_t)(bid * 16 + r) * T_ + t) * D_ + k];
      *(u16*)((char*)Albs + r * 1024 + ((k * 2) ^ ((r & 7) << 4))) = f2h(xv);
    } else {
      int r = tid >> 6, seg = tid & 63;
      uint2 v = *(const uint2*)(seq + ((((size_t)bid * T_ + t) * 16 + r) << 8) + seg * 4);
      *(uint2*)((char*)Albs + r * 1024 + ((seg * 8) ^ ((r & 7) << 4))) = v;
    }
    __syncthreads();

    f32x4 acc[4];
#pragma unroll
    for (int g = 0; g < 4; ++g) {
      acc[g][0] = bv[g]; acc[g][1] = bv[g]; acc[g][2] = bv[g]; acc[g][3] = bv[g];
    }

#pragma unroll
    for (int kc = 0; kc < NKC; ++kc) {
      if (kc + 1 < NKC) {
        u16* nd = ((kc + 1) & 1) ? wdst1 : wdst0;
#pragma unroll
        for (int g = 0; g < 4; ++g)
          gld16(wsrc + (size_t)(kc + 1) * 32768 + g * 512, nd + g * 512);
        asm volatile("s_waitcnt vmcnt(4)" ::: "memory");
      } else {
        asm volatile("s_waitcnt vmcnt(0)" ::: "memory");
      }
      __builtin_amdgcn_sched_barrier(0);

      v8hf a = *(const v8hf*)((const char*)Albs + arow * 1024 +
                              ((kc * 64 + ahi * 16) ^ aswz));
      const u16* wl = ((kc & 1) ? wdst1 : wdst0) + lane * 8;
#pragma unroll
      for (int g = 0; g < 4; ++g) {
        v8hf bw = *(const v8hf*)(const void*)(wl + g * 512);
        acc[g] = __builtin_amdgcn_mfma_f32_16x16x32_f16(a, bw, acc[g], 0, 0, 0);
      }
    }
    __syncthreads();

    __builtin_amdgcn_sched_barrier(0);
#pragma unroll
    for (int g = 0; g < 4; ++g) gld16(wsrc + g * 512, wdst0 + g * 512);

    u16* sbase = seq + ((((size_t)bid * T_ + t) * 16) << 8) + j;
#pragma unroll
    for (int q = 0; q < 4; ++q) {
      int r = ahi * 4 + q;
      float cn = fsig(acc[1][q]) * c[q] + fsig(acc[0][q]) * ftanh(acc[2][q]);
      c[q] = cn;
      float h = fsig(acc[3][q]) * ftanh(cn);
      u16 hb = f2h(h);
      sbase[(size_t)r << 8] = hb;
      *(u16*)((char*)Albs + r * 1024 + (((KX + j) * 2) ^ ((r & 7) << 4))) = hb;
    }
  }
}

// =====================================================================
// ==========================  v9 path  ================================
// =====================================================================
// Packing: frag(kc,cg,g)[lane][i] = W[g*256+cg*16+(lane&15)][kc*32+(lane>>4)*8+i]
// which=0 -> Whh (K=256, 8 kc);  which=1 -> Wih (l=0: K=64, 2 kc; else K=256, 8 kc)
__global__ void pack_weights_v9(const float* __restrict__ Wih0,
                                const float* __restrict__ Wih,
                                const float* __restrict__ Whh,
                                u16* __restrict__ wfh,
                                u16* __restrict__ wfx) {
  int gid = blockIdx.x * 256 + threadIdx.x;
  int lw  = gid >> 15;                   // l*2 + which
  if (lw >= NL_ * 2) return;
  int l = lw >> 1, which = lw & 1;
  int rem  = gid & 32767;
  int kc   = rem >> 12;                  // 0..7
  int cg   = (rem >> 8) & 15;
  int g    = (rem >> 6) & 3;
  int lane = rem & 63;
  if (which == 1 && l == 0 && kc >= 2) return;

  int row = g * 256 + cg * 16 + (lane & 15);
  int k0  = kc * 32 + (lane >> 4) * 8;

  float v[8];
#pragma unroll
  for (int i = 0; i < 8; ++i) {
    int k = k0 + i;
    float x;
    if (which == 0)      x = Whh[(size_t)(l * 1024 + row) * 256 + k];
    else if (l == 0)     x = Wih0[row * 64 + k];
    else                 x = Wih[(size_t)((l - 1) * 1024 + row) * 256 + k];
    v[i] = x;
  }
  u32 pk[4];
#pragma unroll
  for (int i = 0; i < 4; ++i)
    pk[i] = (u32)f2h(v[2 * i]) | ((u32)f2h(v[2 * i + 1]) << 16);
  uint4 val; val.x = pk[0]; val.y = pk[1]; val.z = pk[2]; val.w = pk[3];
  u16* base = (which == 0) ? wfh : wfx;
  u16* dst = base + (size_t)l * WFL9
                  + ((size_t)(kc * 16 + cg) * 4 + g) * 512 + (size_t)lane * 8;
  *(uint4*)dst = val;
}

// One block = 16 batch rows, 1024 thr = 16 waves. Wave wid owns h-cols
// wid*16+arow across all 4 gates. Per 4-step chunk: phase-0 computes
// xg[t][col][r] = bias + x_t @ Wih^T (batched over the chunk, Wih streamed
// through the same LDS ring), then 4 sequential t-steps consume xg and do
// h @ Whh^T (K=256, 8 kc, counted vmcnt DMA ring). Gate accs in registers.
template <bool L0>
__global__ __launch_bounds__(1024, 4) void lstm_layer_v9(
    const float* __restrict__ X,
    u16* __restrict__ seq,
    const u16* __restrict__ wfx_l,    // this layer's Wih frags
    const u16* __restrict__ wfh_l,    // this layer's Whh frags
    u16* __restrict__ xg,             // [NBLK][TCH][1024][16] fp16
    const float* __restrict__ bias) {
  __shared__ __align__(16) u16 Wbuf[2][32768];   // 128 KiB ring
  __shared__ __align__(16) u16 Ah[16 * 256];     // 8 KiB  (h matrix, swizzled)

  const int tid  = threadIdx.x;
  const int wid  = tid >> 6;
  const int lane = tid & 63;
  const int bid  = blockIdx.x;
  const int arow = lane & 15;
  const int ahi  = lane >> 4;
  const int j    = wid * 16 + arow;     // owned h column

  // zero Ah (h=0 at t=0)
  *(uint2*)((char*)Ah + tid * 8) = make_uint2(0, 0);

  float c[4] = {0.f, 0.f, 0.f, 0.f};
  float bv[4];
#pragma unroll
  for (int g = 0; g < 4; ++g) bv[g] = bias[g * 256 + j];

  u16* wdst0 = &Wbuf[0][wid * 2048];
  u16* wdst1 = &Wbuf[1][wid * 2048];
  const size_t laneoff = (size_t)lane * 8;
  u16* xgb = xg + (size_t)bid * 65536;
  uint2 xr[4];

  __syncthreads();

  for (int tc = 0; tc < T_ / TCH; ++tc) {
    // ================= phase 0: xg for chunk tc =================
    f32x4 acc0[TCH][4];
#pragma unroll
    for (int rf = 0; rf < TCH; ++rf)
#pragma unroll
      for (int g = 0; g < 4; ++g) {
        acc0[rf][g][0] = bv[g]; acc0[rf][g][1] = bv[g];
        acc0[rf][g][2] = bv[g]; acc0[rf][g][3] = bv[g];
      }

    if constexpr (L0) {
      // K=64: stage both kc slices, then compute (latency exposed once/chunk)
#pragma unroll
      for (int g = 0; g < 4; ++g) {
        gld16(wfx_l + ((size_t)(0 * 16 + wid) * 4 + g) * 512 + laneoff, wdst0 + g * 512);
        gld16(wfx_l + ((size_t)(1 * 16 + wid) * 4 + g) * 512 + laneoff, wdst1 + g * 512);
      }
      asm volatile("s_waitcnt vmcnt(0)" ::: "memory");
      __builtin_amdgcn_sched_barrier(0);
      const float* xb = X + ((size_t)(bid * 16 + arow) * T_ + tc * TCH) * D_ + ahi * 8;
#pragma unroll
      for (int kc = 0; kc < 2; ++kc) {
        const u16* wl = (kc ? wdst1 : wdst0) + lane * 8;
        v8hf af[TCH];
#pragma unroll
        for (int rf = 0; rf < TCH; ++rf) {
          float4 u = *(const float4*)(xb + rf * D_ + kc * 32);
          float4 v2 = *(const float4*)(xb + rf * D_ + kc * 32 + 4);
          v8hf a;
          a[0] = (_Float16)u.x;  a[1] = (_Float16)u.y;
          a[2] = (_Float16)u.z;  a[3] = (_Float16)u.w;
          a[4] = (_Float16)v2.x; a[5] = (_Float16)v2.y;
          a[6] = (_Float16)v2.z; a[7] = (_Float16)v2.w;
          af[rf] = a;
        }
#pragma unroll
        for (int g = 0; g < 4; ++g) {
          v8hf w = *(const v8hf*)(const void*)(wl + g * 512);
#pragma unroll
          for (int rf = 0; rf < TCH; ++rf)
            acc0[rf][g] = __builtin_amdgcn_mfma_f32_16x16x32_f16(af[rf], w, acc0[rf][g], 0, 0, 0);
        }
      }
    } else {
      // K=256: 8 kc, double-buffered W (LDS ring) + A (registers)
      const u16* abase = seq + ((size_t)(bid * T_ + tc * TCH) * 16 + arow) * 256 + ahi * 8;
      v8hf aA[TCH], aB[TCH];
#pragma unroll
      for (int g = 0; g < 4; ++g)
        gld16(wfx_l + ((size_t)(0 * 16 + wid) * 4 + g) * 512 + laneoff, wdst0 + g * 512);
#pragma unroll
      for (int rf = 0; rf < TCH; ++rf)
        aA[rf] = *(const v8hf*)(const void*)(abase + rf * 4096);

#pragma unroll
      for (int kc = 0; kc < 8; ++kc) {
        if (kc < 7) {
          u16* nd = ((kc + 1) & 1) ? wdst1 : wdst0;
#pragma unroll
          for (int g = 0; g < 4; ++g)
            gld16(wfx_l + ((size_t)((kc + 1) * 16 + wid) * 4 + g) * 512 + laneoff, nd + g * 512);
          if ((kc & 1) == 0) {
#pragma unroll
            for (int rf = 0; rf < TCH; ++rf)
              aB[rf] = *(const v8hf*)(const void*)(abase + rf * 4096 + (kc + 1) * 32);
          } else {
#pragma unroll
            for (int rf = 0; rf < TCH; ++rf)
              aA[rf] = *(const v8hf*)(const void*)(abase + rf * 4096 + (kc + 1) * 32);
          }
          asm volatile("s_waitcnt vmcnt(8)" ::: "memory");
        } else {
          asm volatile("s_waitcnt vmcnt(0)" ::: "memory");
        }
        __builtin_amdgcn_sched_barrier(0);
        const u16* wl = ((kc & 1) ? wdst1 : wdst0) + lane * 8;
#pragma unroll
        for (int g = 0; g < 4; ++g) {
          v8hf w = *(const v8hf*)(const void*)(wl + g * 512);
#pragma unroll
          for (int rf = 0; rf < TCH; ++rf)
            acc0[rf][g] = __builtin_amdgcn_mfma_f32_16x16x32_f16(
                ((kc & 1) ? aB[rf] : aA[rf]), w, acc0[rf][g], 0, 0, 0);
        }
      }
    }

    // store xg (transposed [t][col][r]); bias already folded in
#pragma unroll
    for (int rf = 0; rf < TCH; ++rf)
#pragma unroll
      for (int g = 0; g < 4; ++g) {
        uint2 pk;
        pk.x = (u32)f2h(acc0[rf][g][0]) | ((u32)f2h(acc0[rf][g][1]) << 16);
        pk.y = (u32)f2h(acc0[rf][g][2]) | ((u32)f2h(acc0[rf][g][3]) << 16);
        *(uint2*)(xgb + (((size_t)(rf * 1024 + g * 256 + j)) << 4) + ahi * 4) = pk;
      }
    __syncthreads();   // xg stores drained (compiler), Wbuf free

    // prologue for tl=0: xg loads + stage Whh kc0
#pragma unroll
    for (int g = 0; g < 4; ++g)
      xr[g] = *(const uint2*)(xgb + (((size_t)(0 * 1024 + g * 256 + j)) << 4) + ahi * 4);
#pragma unroll
    for (int g = 0; g < 4; ++g)
      gld16(wfh_l + ((size_t)(0 * 16 + wid) * 4 + g) * 512 + laneoff, wdst0 + g * 512);

    // ================= t-steps =================
    for (int tl = 0; tl < TCH; ++tl) {
      const int t = tc * TCH + tl;
      f32x4 acc[4];
#pragma unroll
      for (int g = 0; g < 4; ++g) {
        acc[g][0] = h2f((u16)(xr[g].x & 0xffff));
        acc[g][1] = h2f((u16)(xr[g].x >> 16));
        acc[g][2] = h2f((u16)(xr[g].y & 0xffff));
        acc[g][3] = h2f((u16)(xr[g].y >> 16));
      }

#pragma unroll
      for (int kc = 0; kc < 8; ++kc) {
        if (kc < 7) {
          u16* nd = ((kc + 1) & 1) ? wdst1 : wdst0;
#pragma unroll
          for (int g = 0; g < 4; ++g)
            gld16(wfh_l + ((size_t)((kc + 1) * 16 + wid) * 4 + g) * 512 + laneoff, nd + g * 512);
          asm volatile("s_waitcnt vmcnt(4)" ::: "memory");
        } else {
          asm volatile("s_waitcnt vmcnt(0)" ::: "memory");
        }
        __builtin_amdgcn_sched_barrier(0);

        v8hf a = *(const v8hf*)((const char*)Ah + arow * 512 +
                                ((kc * 64 + ahi * 16) ^ ((arow & 7) << 4)));
        const u16* wl = ((kc & 1) ? wdst1 : wdst0) + lane * 8;
#pragma unroll
        for (int g = 0; g < 4; ++g) {
          v8hf w = *(const v8hf*)(const void*)(wl + g * 512);
          acc[g] = __builtin_amdgcn_mfma_f32_16x16x32_f16(a, w, acc[g], 0, 0, 0);
        }
      }
      __syncthreads();   // all Ah reads done before overwrite

      if (tl + 1 < TCH) {   // prologue for next step (hides under phase-3 VALU)
#pragma unroll
        for (int g = 0; g < 4; ++g)
          xr[g] = *(const uint2*)(xgb + (((size_t)((tl + 1) * 1024 + g * 256 + j)) << 4) + ahi * 4);
        __builtin_amdgcn_sched_barrier(0);
#pragma unroll
        for (int g = 0; g < 4; ++g)
          gld16(wfh_l + ((size_t)(0 * 16 + wid) * 4 + g) * 512 + laneoff, wdst0 + g * 512);
      }

      // phase 3: nonlinearity + state update (lane: col j, rows ahi*4+q)
      u16* sbase = seq + ((((size_t)bid * T_ + t) * 16) << 8) + j;
#pragma unroll
      for (int q = 0; q < 4; ++q) {
        int r = ahi * 4 + q;
        float cn = fsig(acc[1][q]) * c[q] + fsig(acc[0][q]) * ftanh(acc[2][q]);
        c[q] = cn;
        float h = fsig(acc[3][q]) * ftanh(cn);
        u16 hb = f2h(h);
        sbase[(size_t)r << 8] = hb;
        *(u16*)((char*)Ah + r * 512 + ((j * 2) ^ ((r & 7) << 4))) = hb;
      }
      __syncthreads();   // Ah ready for next step; prologue stages drained
    }
  }
}

// ---------------- tail (encoder / sample / decoder) ----------------
template <int N, int K, bool RELU>
__device__ __forceinline__ void dense(const float (*__restrict__ in)[512],
                                      float (*__restrict__ out)[512],
                                      const float* __restrict__ W,
                                      const float* __restrict__ bg, int tid) {
  for (int e = tid; e < 16 * N; e += 256) {
    int r = e / N, n = e - r * N;
    const float* wr = W + (size_t)n * K;
    const float* ar = in[r];
    float4 acc = {0.f, 0.f, 0.f, 0.f};
    for (int k = 0; k < K; k += 4) {
      float4 wv = *(const float4*)(wr + k);
      float4 av = *(const float4*)(ar + k);
      acc.x = fmaf(wv.x, av.x, acc.x);
      acc.y = fmaf(wv.y, av.y, acc.y);
      acc.z = fmaf(wv.z, av.z, acc.z);
      acc.w = fmaf(wv.w, av.w, acc.w);
    }
    float s = bg[n] + acc.x + acc.y + acc.z + acc.w;
    out[r][n] = RELU ? fmaxf(s, 0.f) : s;
  }
}

template <int K>
__device__ __forceinline__ float dotK(const float* __restrict__ a, const float* __restrict__ w) {
  float4 acc = {0.f, 0.f, 0.f, 0.f};
#pragma unroll
  for (int k = 0; k < K; k += 4) {
    float4 wv = *(const float4*)(w + k);
    float4 av = *(const float4*)(a + k);
    acc.x = fmaf(wv.x, av.x, acc.x);
    acc.y = fmaf(wv.y, av.y, acc.y);
    acc.z = fmaf(wv.z, av.z, acc.z);
    acc.w = fmaf(wv.w, av.w, acc.w);
  }
  return acc.x + acc.y + acc.z + acc.w;
}

struct TailArgs {
  const u16* seq;
  const float *ef1w, *ef1b, *ef2w, *ef2b;
  const float *mean_w, *mean_b, *logvar_w, *logvar_b;
  const float *scale_w, *scale_b, *shape_w, *shape_b;
  const float *df1w, *df1b, *df2w, *df2b, *outw, *outb, *finw, *finb;
  const float *pi, *eps, *u, *choice;
  float* out;
};

__global__ __launch_bounds__(256) void tail_kernel_v8(TailArgs A) {
  __shared__ float a0[16][512];
  __shared__ float a1[16][512];
  const int tid = threadIdx.x, bid = blockIdx.x;

  for (int e = tid; e < 16 * 256; e += 256) {
    int r = e >> 8, jj = e & 255;
    a0[r][jj] = h2f(A.seq[((((size_t)bid * T_ + (T_ - 1)) * 16 + r) << 8) + jj]);
  }
  __syncthreads();

  dense<128, 256, true>(a0, a1, A.ef1w, A.ef1b, tid); __syncthreads();
  dense<64, 128, true>(a1, a0, A.ef2w, A.ef2b, tid);  __syncthreads();

  const float pi = *A.pi;
  for (int e = tid; e < 16 * 64; e += 256) {
    int r = e >> 6, n = e & 63;
    size_t rg = (size_t)bid * 16 + r;
    float m  = dotK<64>(a0[r], A.mean_w   + n * 64) + A.mean_b[n];
    float lv = dotK<64>(a0[r], A.logvar_w + n * 64) + A.logvar_b[n];
    float sc = __expf(dotK<64>(a0[r], A.scale_w + n * 64) + A.scale_b[n]);
    float sh = dotK<64>(a0[r], A.shape_w + n * 64) + A.shape_b[n];
    A.out[196608 + rg * 64 + n] = m;
    A.out[327680 + rg * 64 + n] = lv;
    A.out[458752 + rg * 64 + n] = sc;
    A.out[589824 + rg * 64 + n] = sh;
    float zg = m + A.eps[rg * 64 + n] * __expf(0.5f * lv);
    float L  = log1pf(-A.u[rg * 64 + n]);
    float zp = sc / sh * (__expf(-sh * L) - 1.f);
    a1[r][n] = (A.choice[rg] < pi) ? zg : zp;
  }
  __syncthreads();

  dense<128, 64, true>(a1, a0, A.df1w, A.df1b, tid);   __syncthreads();
  dense<500, 128, true>(a0, a1, A.df2w, A.df2b, tid);  __syncthreads();
  dense<96, 500, false>(a1, a0, A.outw, A.outb, tid);  __syncthreads();
  dense<96, 96, false>(a0, a1, A.finw, A.finb, tid);   __syncthreads();

  for (int e = tid; e < 16 * FUT_; e += 256) {
    int r = e / FUT_, n = e - r * FUT_;
    A.out[((size_t)bid * 16 + r) * FUT_ + n] = a1[r][n];
  }
}

// ---------------- launch ----------------
extern "C" void kernel_launch(void* const* d_in, const int* in_sizes, int n_in,
                              void* d_out, int out_size, void* d_ws, size_t ws_size,
                              hipStream_t stream) {
  (void)in_sizes; (void)n_in; (void)out_size;

  const float* X      = (const float*)d_in[0];
  const float* Wih0   = (const float*)d_in[1];
  const float* Wih    = (const float*)d_in[2];
  const float* Whh    = (const float*)d_in[3];
  const float* b      = (const float*)d_in[4];
  const float* ef1w   = (const float*)d_in[5];
  const float* ef1b   = (const float*)d_in[6];
  const float* ef2w   = (const float*)d_in[7];
  const float* ef2b   = (const float*)d_in[8];
  const float* mean_w = (const float*)d_in[9];
  const float* mean_b = (const float*)d_in[10];
  const float* logvar_w = (const float*)d_in[11];
  const float* logvar_b = (const float*)d_in[12];
  const float* scale_w  = (const float*)d_in[13];
  const float* scale_b  = (const float*)d_in[14];
  const float* shape_w  = (const float*)d_in[15];
  const float* shape_b  = (const float*)d_in[16];
  const float* df1w   = (const float*)d_in[17];
  const float* df1b   = (const float*)d_in[18];
  const float* df2w   = (const float*)d_in[19];
  const float* df2b   = (const float*)d_in[20];
  const float* outw   = (const float*)d_in[21];
  const float* outb   = (const float*)d_in[22];
  const float* finw   = (const float*)d_in[23];
  const float* finb   = (const float*)d_in[24];
  const float* pi_g   = (const float*)d_in[25];
  const float* eps    = (const float*)d_in[26];
  const float* u      = (const float*)d_in[27];
  const float* choice = (const float*)d_in[28];

  float* out = (float*)d_out;
  const bool big = ws_size >= WS_NEED_V9;
  u16* seq;

  if (big) {
    u16* wfh = (u16*)((char*)d_ws + WFH_OFF);
    u16* wfx = (u16*)((char*)d_ws + WFX_OFF);
    u16* xg  = (u16*)((char*)d_ws + XG_OFF);
    seq      = (u16*)((char*)d_ws + SEQ2_OFF);

    pack_weights_v9<<<2560, 256, 0, stream>>>(Wih0, Wih, Whh, wfh, wfx);

    lstm_layer_v9<true><<<NBLK, 1024, 0, stream>>>(X, seq, wfx, wfh, xg, b);
    for (int l = 1; l < NL_; ++l)
      lstm_layer_v9<false><<<NBLK, 1024, 0, stream>>>(nullptr, seq,
          wfx + (size_t)l * WFL9, wfh + (size_t)l * WFL9, xg, b + l * 1024);
  } else {
    u16* wf = (u16*)d_ws;
    seq     = (u16*)((char*)d_ws + SEQ_OFF);

    pack_weights_v8<<<2560, 256, 0, stream>>>(Wih0, Wih, Whh, wf);

    lstm_layer_v8<10, 64, true><<<NBLK, 1024, 0, stream>>>(X, seq, wf, b);
    for (int l = 1; l < NL_; ++l)
      lstm_layer_v8<16, 256, false><<<NBLK, 1024, 0, stream>>>(nullptr, seq,
          wf + (size_t)l * WF_LAYER_ELEMS, b + l * 1024);
  }

  TailArgs A;
  A.seq = seq;
  A.ef1w = ef1w; A.ef1b = ef1b; A.ef2w = ef2w; A.ef2b = ef2b;
  A.mean_w = mean_w; A.mean_b = mean_b; A.logvar_w = logvar_w; A.logvar_b = logvar_b;
  A.scale_w = scale_w; A.scale_b = scale_b; A.shape_w = shape_w; A.shape_b = shape_b;
  A.df1w = df1w; A.df1b = df1b; A.df2w = df2w; A.df2b = df2b;
  A.outw = outw; A.outb = outb; A.finw = finw; A.finb = finb;
  A.pi = pi_g; A.eps = eps; A.u = u; A.choice = choice;
  A.out = out;
  tail_kernel_v8<<<NBLK, 256, 0, stream>>>(A);
}